// Round 4
// baseline (544.514 us; speedup 1.0000x reference)
//
#include <hip/hip_runtime.h>
#include <hip/hip_bf16.h>

typedef __bf16 bf16_t;
typedef bf16_t bf16x8 __attribute__((ext_vector_type(8)));
typedef bf16_t bf16x4 __attribute__((ext_vector_type(4)));
typedef bf16_t bf16x2 __attribute__((ext_vector_type(2)));
typedef float f32x4 __attribute__((ext_vector_type(4)));

#define EPS_BN 1e-5f
#define EPS_LN 1e-5f
#define SLOTS 32
#define NPASS 8
#define WSCALE 32767.f
#define WINV (1.f / 32767.f)

__device__ __forceinline__ float blo(unsigned u) { return __uint_as_float(u << 16); }
__device__ __forceinline__ float bhi(unsigned u) { return __uint_as_float(u & 0xFFFF0000u); }

// ---------------- weight convert: 4x W[i][o] fp32 -> WT[o*136+i] bf16 (padded) ----------------

__global__ void convertAllK(const float* __restrict__ W0, const float* __restrict__ W1,
                            const float* __restrict__ W2, const float* __restrict__ W3,
                            bf16_t* __restrict__ WT) {
    int flat = blockIdx.x * 256 + threadIdx.x;   // 0..65535
    int which = flat >> 14, r = flat & 16383;
    const float* W = (which == 0) ? W0 : (which == 1) ? W1 : (which == 2) ? W2 : W3;
    int i = r >> 7, o = r & 127;
    WT[which * 128 * 136 + o * 136 + i] = (bf16_t)W[r];
}

// ---------------- adjacency fill, one dst-range pass (L2-resident scatter) ----------------
// slot entry: (src << 15) | round(w * 32767), w in [0,1)

__global__ __launch_bounds__(256) void fillPassK(
    const int* __restrict__ ei, const float* __restrict__ ea,
    int* __restrict__ cnt, unsigned* __restrict__ slots,
    uint2* __restrict__ ov, int* __restrict__ ovCnt, int E, int lo, int hi)
{
    int e = blockIdx.x * 256 + threadIdx.x;
    if (e >= E) return;
    int d = ei[E + e];          // edge_index[1][e]
    if (d < lo || d >= hi) return;
    int s = ei[e];              // edge_index[0][e]
    unsigned wq = __float2uint_rn(ea[e] * WSCALE);
    unsigned pk = ((unsigned)s << 15) | wq;
    int pos = atomicAdd(&cnt[d], 1);
    if (pos < SLOTS) {
        slots[(d << 5) + pos] = pk;
    } else {
        int o = atomicAdd(ovCnt, 1);
        ov[o] = make_uint2((unsigned)d, pk);
    }
}

// deg[n] = 1 + sum of slot weights (+overflow); dinv = rsqrt(deg). Half-wave per node.
__global__ __launch_bounds__(256) void degDinvK(
    const unsigned* __restrict__ slots, const int* __restrict__ cnt,
    const uint2* __restrict__ ov, const int* __restrict__ ovCnt,
    float* __restrict__ dinv, int n)
{
    int tid = threadIdx.x;
    int node = blockIdx.x * 8 + (tid >> 5);
    int hl = tid & 31;
    if (node >= n) return;
    int c = min(cnt[node], SLOTS);
    float w = 0.f;
    if (hl < c) w = (float)(slots[(node << 5) + hl] & 32767u) * WINV;
    for (int off = 1; off < 32; off <<= 1) w += __shfl_xor(w, off);
    int no = *ovCnt;
    for (int k = 0; k < no; ++k) {
        uint2 o = ov[k];
        if ((int)o.x == node) w += (float)(o.y & 32767u) * WINV;
    }
    if (hl == 0) dinv[node] = rsqrtf(fmaxf(1.f + w, 1e-12f));
}

// ---------------- GEMM: out[r][j] = epilogue( sum_k A[r][k]*W[k][j] ), bf16 out ----------------
// MODE 0: BN(acc + colBias) then ReLU   (input preprocess, A fp32)
// MODE 1: acc * dinv[row]               (pre-scaled conv message, A bf16)
// MODE 2: acc + colBias                 (classifier linear 1, A bf16)

template <int MODE, typename AT>
__global__ __launch_bounds__(256) void gemm128K(
    const AT* __restrict__ A, const bf16_t* __restrict__ WT,
    bf16_t* __restrict__ out,
    const float* __restrict__ colBias,
    const float* __restrict__ bnMean, const float* __restrict__ bnVar,
    const float* __restrict__ bnG, const float* __restrict__ bnB,
    const float* __restrict__ dinv, int nrows)
{
    __shared__ __align__(16) bf16_t As[64 * 136];
    __shared__ __align__(16) bf16_t Bs[128 * 136];
    int tid = threadIdx.x;
    int rb = blockIdx.x * 64;

    // stage WT (already padded, 128*136 bf16) straight into LDS
    {
        const uint4* src = (const uint4*)WT;
        uint4* dst = (uint4*)Bs;
        for (int i = tid; i < (128 * 136 * 2) / 16; i += 256) dst[i] = src[i];
    }
    // stage A tile (64 rows x 128 cols -> bf16, padded stride 136)
    if constexpr (sizeof(AT) == 4) {
        for (int it = 0; it < 8; ++it) {
            int flat = it * 1024 + tid * 4;
            int r = flat >> 7, c = flat & 127;
            int row = rb + r;
            float4 v;
            if (row < nrows) v = ((const float4*)A)[row * 32 + (c >> 2)];
            else             v = make_float4(0.f, 0.f, 0.f, 0.f);
            bf16x4 w4;
            w4.x = (bf16_t)v.x; w4.y = (bf16_t)v.y; w4.z = (bf16_t)v.z; w4.w = (bf16_t)v.w;
            *(bf16x4*)&As[r * 136 + c] = w4;
        }
    } else {
        for (int it = 0; it < 4; ++it) {
            int flat = it * 2048 + tid * 8;
            int r = flat >> 7, c = flat & 127;
            int row = rb + r;
            bf16x8 v = (bf16x8)(bf16_t)0.f;
            if (row < nrows) v = ((const bf16x8*)A)[row * 16 + (c >> 3)];
            *(bf16x8*)&As[r * 136 + c] = v;
        }
    }
    __syncthreads();

    int lane = tid & 63;
    int wid = tid >> 6;
    int m = lane & 15, q = lane >> 4;

    f32x4 acc[8];
#pragma unroll
    for (int c = 0; c < 8; ++c) acc[c] = (f32x4){0.f, 0.f, 0.f, 0.f};

    const bf16_t* aRow = &As[(wid * 16 + m) * 136 + q * 8];
#pragma unroll
    for (int kk = 0; kk < 4; ++kk) {
        bf16x8 af = *(const bf16x8*)(aRow + kk * 32);
#pragma unroll
        for (int c = 0; c < 8; ++c) {
            bf16x8 bfr = *(const bf16x8*)&Bs[(c * 16 + m) * 136 + q * 8 + kk * 32];
            acc[c] = __builtin_amdgcn_mfma_f32_16x16x32_bf16(af, bfr, acc[c], 0, 0, 0);
        }
    }

    int r0 = rb + wid * 16 + q * 4;
    float dv[4];
    if (MODE == 1) {
#pragma unroll
        for (int i = 0; i < 4; ++i) dv[i] = (r0 + i < nrows) ? dinv[r0 + i] : 0.f;
    }
#pragma unroll
    for (int c = 0; c < 8; ++c) {
        int j = c * 16 + m;
        float cb = 0.f, scale = 1.f, shift = 0.f;
        if (MODE == 0) {
            cb = colBias[j];
            float rs = rsqrtf(bnVar[j] + EPS_BN);
            scale = bnG[j] * rs;
            shift = bnB[j] - bnMean[j] * scale;
        } else if (MODE == 2) {
            cb = colBias[j];
        }
#pragma unroll
        for (int i = 0; i < 4; ++i) {
            int r = r0 + i;
            if (r < nrows) {
                float v = acc[c][i];
                if (MODE == 0) { v = (v + cb) * scale + shift; v = fmaxf(v, 0.f); }
                else if (MODE == 1) { v = v * dv[i]; }
                else { v = v + cb; }
                out[r * 128 + j] = (bf16_t)v;
            }
        }
    }
}

// ---------------- aggregation (half-wave per node): ----------------
// out[d] = act(dinv[d]*(ts[d] + sum w*ts[src]) + b (+res))
// 32 lanes x uint2 (4 bf16) covers one 256 B node row; one wave = 2 nodes.

template <int RELU, int RES>
__global__ __launch_bounds__(256) void aggK(
    const uint2* __restrict__ ts, const unsigned* __restrict__ slots,
    const int* __restrict__ cnt, const float* __restrict__ dinv,
    const float4* __restrict__ bias, const uint2* __restrict__ residual,
    uint2* __restrict__ out,
    const uint2* __restrict__ ov, const int* __restrict__ ovCnt, int n)
{
    int tid = threadIdx.x;
    int node = blockIdx.x * 8 + (tid >> 5);
    int hl = tid & 31;          // lane within half-wave
    int hb = tid & 32;          // 0 or 32: base lane of my half within the wave
    if (node >= n) return;
    int nb = node << 5;

    uint2 sv = ts[nb | hl];     // self-loop term
    float a0 = blo(sv.x), a1 = bhi(sv.x), a2 = blo(sv.y), a3 = bhi(sv.y);

    int c = min(cnt[node], SLOTS);
    unsigned my = slots[nb | hl];   // lane hl holds slot hl (first c valid)

    int j = 0;
    for (; j + 3 < c; j += 4) {
        unsigned p0 = __shfl(my, hb | j);
        unsigned p1 = __shfl(my, hb | (j + 1));
        unsigned p2 = __shfl(my, hb | (j + 2));
        unsigned p3 = __shfl(my, hb | (j + 3));
        uint2 v0 = ts[((p0 >> 15) << 5) | hl];
        uint2 v1 = ts[((p1 >> 15) << 5) | hl];
        uint2 v2 = ts[((p2 >> 15) << 5) | hl];
        uint2 v3 = ts[((p3 >> 15) << 5) | hl];
        float w0 = (float)(p0 & 32767u) * WINV;
        float w1 = (float)(p1 & 32767u) * WINV;
        float w2 = (float)(p2 & 32767u) * WINV;
        float w3 = (float)(p3 & 32767u) * WINV;
        a0 += w0 * blo(v0.x) + w1 * blo(v1.x) + w2 * blo(v2.x) + w3 * blo(v3.x);
        a1 += w0 * bhi(v0.x) + w1 * bhi(v1.x) + w2 * bhi(v2.x) + w3 * bhi(v3.x);
        a2 += w0 * blo(v0.y) + w1 * blo(v1.y) + w2 * blo(v2.y) + w3 * blo(v3.y);
        a3 += w0 * bhi(v0.y) + w1 * bhi(v1.y) + w2 * bhi(v2.y) + w3 * bhi(v3.y);
    }
    for (; j < c; ++j) {
        unsigned p0 = __shfl(my, hb | j);
        uint2 v0 = ts[((p0 >> 15) << 5) | hl];
        float w0 = (float)(p0 & 32767u) * WINV;
        a0 += w0 * blo(v0.x);
        a1 += w0 * bhi(v0.x);
        a2 += w0 * blo(v0.y);
        a3 += w0 * bhi(v0.y);
    }
    int no = *ovCnt;
    for (int k = 0; k < no; ++k) {
        uint2 o = ov[k];
        if ((int)o.x == node) {
            uint2 v = ts[((o.y >> 15) << 5) | hl];
            float w = (float)(o.y & 32767u) * WINV;
            a0 += w * blo(v.x);
            a1 += w * bhi(v.x);
            a2 += w * blo(v.y);
            a3 += w * bhi(v.y);
        }
    }

    float di = dinv[node];
    float4 bb = bias[hl];
    float r0 = a0 * di + bb.x;
    float r1 = a1 * di + bb.y;
    float r2 = a2 * di + bb.z;
    float r3 = a3 * di + bb.w;
    if (RES) {
        uint2 rr = residual[nb | hl];
        r0 += blo(rr.x); r1 += bhi(rr.x); r2 += blo(rr.y); r3 += bhi(rr.y);
    }
    if (RELU) {
        r0 = fmaxf(r0, 0.f); r1 = fmaxf(r1, 0.f);
        r2 = fmaxf(r2, 0.f); r3 = fmaxf(r3, 0.f);
    }
    bf16x4 o4;
    o4.x = (bf16_t)r0; o4.y = (bf16_t)r1; o4.z = (bf16_t)r2; o4.w = (bf16_t)r3;
    out[nb | hl] = *(uint2*)&o4;
}

// ---------------- final: LayerNorm -> ReLU -> Linear(128->3) ----------------

__global__ __launch_bounds__(256) void finalK(
    const bf16_t* __restrict__ Z, const float* __restrict__ g,
    const float* __restrict__ b, const float* __restrict__ Wc2,
    const float* __restrict__ bc2, float* __restrict__ out, int n)
{
    int node = blockIdx.x * 4 + (threadIdx.x >> 6);
    int lane = threadIdx.x & 63;
    if (node >= n) return;
    bf16x2 z2 = ((const bf16x2*)Z)[(node << 6) + lane];
    float zx0 = (float)z2.x, zy0 = (float)z2.y;
    float s1 = zx0 + zy0;
    float s2 = zx0 * zx0 + zy0 * zy0;
    for (int off = 1; off < 64; off <<= 1) {
        s1 += __shfl_xor(s1, off);
        s2 += __shfl_xor(s2, off);
    }
    float mu = s1 * (1.f / 128.f);
    float var = s2 * (1.f / 128.f) - mu * mu;
    float rstd = rsqrtf(var + EPS_LN);
    float zx = fmaxf((zx0 - mu) * rstd * g[2 * lane] + b[2 * lane], 0.f);
    float zy = fmaxf((zy0 - mu) * rstd * g[2 * lane + 1] + b[2 * lane + 1], 0.f);
    float p0 = zx * Wc2[(2 * lane) * 3 + 0] + zy * Wc2[(2 * lane + 1) * 3 + 0];
    float p1 = zx * Wc2[(2 * lane) * 3 + 1] + zy * Wc2[(2 * lane + 1) * 3 + 1];
    float p2 = zx * Wc2[(2 * lane) * 3 + 2] + zy * Wc2[(2 * lane + 1) * 3 + 2];
    for (int off = 1; off < 64; off <<= 1) {
        p0 += __shfl_xor(p0, off);
        p1 += __shfl_xor(p1, off);
        p2 += __shfl_xor(p2, off);
    }
    if (lane == 0) {
        out[node * 3 + 0] = p0 + bc2[0];
        out[node * 3 + 1] = p1 + bc2[1];
        out[node * 3 + 2] = p2 + bc2[2];
    }
}

// ---------------- launch ----------------

extern "C" void kernel_launch(void* const* d_in, const int* in_sizes, int n_in,
                              void* d_out, int out_size, void* d_ws, size_t ws_size,
                              hipStream_t stream) {
    const float* x      = (const float*)d_in[0];
    const int*   ei     = (const int*)d_in[1];
    const float* ea     = (const float*)d_in[2];
    const float* W_pre  = (const float*)d_in[3];
    const float* b_pre  = (const float*)d_in[4];
    const float* bn_g   = (const float*)d_in[5];
    const float* bn_b   = (const float*)d_in[6];
    const float* bn_m   = (const float*)d_in[7];
    const float* bn_v   = (const float*)d_in[8];
    const float* W1     = (const float*)d_in[9];
    const float* b1     = (const float*)d_in[10];
    const float* W2     = (const float*)d_in[11];
    const float* b2     = (const float*)d_in[12];
    const float* Wc1    = (const float*)d_in[13];
    const float* bc1    = (const float*)d_in[14];
    const float* ln_g   = (const float*)d_in[15];
    const float* ln_b   = (const float*)d_in[16];
    const float* Wc2    = (const float*)d_in[17];
    const float* bc2    = (const float*)d_in[18];
    float* outp = (float*)d_out;

    const int N = in_sizes[0] / 128;
    const int E = in_sizes[2];

    char* p = (char*)d_ws;
    auto alloc = [&](size_t bytes) -> void* {
        void* r = (void*)p;
        p += (bytes + 255) & ~(size_t)255;
        return r;
    };
    bf16_t*   h0    = (bf16_t*)alloc((size_t)N * 128 * 2);
    bf16_t*   bufA  = (bf16_t*)alloc((size_t)N * 128 * 2);
    bf16_t*   bufB  = (bf16_t*)alloc((size_t)N * 128 * 2);
    float*    dinv  = (float*)alloc((size_t)N * 4);
    int*      cnt   = (int*)alloc((size_t)N * 4);
    int*      ovCnt = (int*)alloc(256);
    uint2*    ov    = (uint2*)alloc((size_t)4096 * 8);
    unsigned* slots = (unsigned*)alloc((size_t)N * SLOTS * 4);
    bf16_t*   WT    = (bf16_t*)alloc((size_t)4 * 128 * 136 * 2);

    bf16_t* WT_pre = WT + 0 * 128 * 136;
    bf16_t* WT_1   = WT + 1 * 128 * 136;
    bf16_t* WT_2   = WT + 2 * 128 * 136;
    bf16_t* WT_c1  = WT + 3 * 128 * 136;

    int gE = (E + 255) / 256;
    int gG = (N + 63) / 64;
    int gW = (N + 3) / 4;
    int gH = (N + 7) / 8;

    hipMemsetAsync(cnt, 0, (size_t)N * 4, stream);
    hipMemsetAsync(ovCnt, 0, 4, stream);

    convertAllK<<<256, 256, 0, stream>>>(W_pre, W1, W2, Wc1, WT);

    // adjacency fill: NPASS dst-range passes so the scatter region is L2-resident
    int range = (N + NPASS - 1) / NPASS;
    for (int ps = 0; ps < NPASS; ++ps) {
        int lo = ps * range;
        int hi = min(N, lo + range);
        fillPassK<<<gE, 256, 0, stream>>>(ei, ea, cnt, slots, ov, ovCnt, E, lo, hi);
    }
    degDinvK<<<gH, 256, 0, stream>>>(slots, cnt, ov, ovCnt, dinv, N);

    // h0 = relu(bn(x@W_pre + b_pre))
    gemm128K<0, float><<<gG, 256, 0, stream>>>(x, WT_pre, h0, b_pre, bn_m, bn_v, bn_g, bn_b, nullptr, N);
    // conv1
    gemm128K<1, bf16_t><<<gG, 256, 0, stream>>>(h0, WT_1, bufA, nullptr, nullptr, nullptr, nullptr, nullptr, dinv, N);
    aggK<1, 0><<<gH, 256, 0, stream>>>((const uint2*)bufA, slots, cnt, dinv, (const float4*)b1,
                                       nullptr, (uint2*)bufB, ov, ovCnt, N);
    // conv2 (+residual h0)
    gemm128K<1, bf16_t><<<gG, 256, 0, stream>>>(bufB, WT_2, bufA, nullptr, nullptr, nullptr, nullptr, nullptr, dinv, N);
    aggK<0, 1><<<gH, 256, 0, stream>>>((const uint2*)bufA, slots, cnt, dinv, (const float4*)b2,
                                       (const uint2*)h0, (uint2*)bufB, ov, ovCnt, N);
    // z = h@Wc1 + bc1
    gemm128K<2, bf16_t><<<gG, 256, 0, stream>>>(bufB, WT_c1, bufA, bc1, nullptr, nullptr, nullptr, nullptr, nullptr, N);
    // out = relu(LN(z)) @ Wc2 + bc2
    finalK<<<gW, 256, 0, stream>>>(bufA, ln_g, ln_b, Wc2, bc2, outp, N);
}

// Round 5
// 532.321 us; speedup vs baseline: 1.0229x; 1.0229x over previous
//
#include <hip/hip_runtime.h>
#include <hip/hip_bf16.h>

typedef __bf16 bf16_t;
typedef bf16_t bf16x8 __attribute__((ext_vector_type(8)));
typedef bf16_t bf16x4 __attribute__((ext_vector_type(4)));
typedef bf16_t bf16x2 __attribute__((ext_vector_type(2)));
typedef float f32x4 __attribute__((ext_vector_type(4)));

#define EPS_BN 1e-5f
#define EPS_LN 1e-5f
#define SLOTS 32
#define NPASS 4
#define WSCALE 32767.f
#define WINV (1.f / 32767.f)

__device__ __forceinline__ float blo(unsigned u) { return __uint_as_float(u << 16); }
__device__ __forceinline__ float bhi(unsigned u) { return __uint_as_float(u & 0xFFFF0000u); }

// ---------------- weight convert: 4x W[i][o] fp32 -> WT[o*136+i] bf16 (padded) ----------------

__global__ void convertAllK(const float* __restrict__ W0, const float* __restrict__ W1,
                            const float* __restrict__ W2, const float* __restrict__ W3,
                            bf16_t* __restrict__ WT) {
    int flat = blockIdx.x * 256 + threadIdx.x;   // 0..65535
    int which = flat >> 14, r = flat & 16383;
    const float* W = (which == 0) ? W0 : (which == 1) ? W1 : (which == 2) ? W2 : W3;
    int i = r >> 7, o = r & 127;
    WT[which * 128 * 136 + o * 136 + i] = (bf16_t)W[r];
}

// ---------------- adjacency fill, one dst-range pass (L2-resident scatter) ----------------
// slot entry: (src << 15) | round(w * 32767), w in [0,1)

__global__ __launch_bounds__(256) void fillPassK(
    const int* __restrict__ ei, const float* __restrict__ ea,
    int* __restrict__ cnt, unsigned* __restrict__ slots,
    uint2* __restrict__ ov, int* __restrict__ ovCnt, int E, int lo, int hi)
{
    int e = blockIdx.x * 256 + threadIdx.x;
    if (e >= E) return;
    int d = ei[E + e];          // edge_index[1][e]
    if (d < lo || d >= hi) return;
    int s = ei[e];              // edge_index[0][e]
    unsigned wq = __float2uint_rn(ea[e] * WSCALE);
    unsigned pk = ((unsigned)s << 15) | wq;
    int pos = atomicAdd(&cnt[d], 1);
    if (pos < SLOTS) {
        slots[(d << 5) + pos] = pk;
    } else {
        int o = atomicAdd(ovCnt, 1);
        ov[o] = make_uint2((unsigned)d, pk);
    }
}

// dinv = rsqrt(1 + sum w); ALSO bitonic-sorts each slot row by src (ascending)
// so the aggregation sweeps src-space monotonically (L2 moving window).
__global__ __launch_bounds__(256) void degDinvSortK(
    unsigned* __restrict__ slots, const int* __restrict__ cnt,
    const uint2* __restrict__ ov, const int* __restrict__ ovCnt,
    float* __restrict__ dinv, int n)
{
    int tid = threadIdx.x;
    int node = blockIdx.x * 8 + (tid >> 5);
    int hl = tid & 31;
    if (node >= n) return;
    int c = min(cnt[node], SLOTS);
    unsigned v = (hl < c) ? slots[(node << 5) + hl] : 0xFFFFFFFFu;  // invalid -> sort to end
    float w = (hl < c) ? (float)(v & 32767u) * WINV : 0.f;
    for (int off = 1; off < 32; off <<= 1) w += __shfl_xor(w, off);
    // bitonic sort of 32 entries across the half-wave (partners stay in-half: j<32)
#pragma unroll
    for (int k = 2; k <= 32; k <<= 1) {
#pragma unroll
        for (int j = k >> 1; j >= 1; j >>= 1) {
            unsigned o = __shfl_xor(v, j);
            bool up = (hl & k) == 0;        // hl<32 -> k=32 gives up=true for all
            bool keepMin = ((hl & j) == 0) == up;
            unsigned lo_ = (v < o) ? v : o;
            unsigned hi_ = (v < o) ? o : v;
            v = keepMin ? lo_ : hi_;
        }
    }
    slots[(node << 5) + hl] = v;
    int no = *ovCnt;
    for (int k = 0; k < no; ++k) {
        uint2 o = ov[k];
        if ((int)o.x == node) w += (float)(o.y & 32767u) * WINV;
    }
    if (hl == 0) dinv[node] = rsqrtf(fmaxf(1.f + w, 1e-12f));
}

// ---------------- GEMM: out[r][j] = epilogue( sum_k A[r][k]*W[k][j] ), bf16 out ----------------
// MODE 0: BN(acc + colBias) then ReLU   (input preprocess, A fp32)
// MODE 1: acc * dinv[row]               (pre-scaled conv message, A bf16)
// MODE 2: acc + colBias                 (classifier linear 1, A bf16)

template <int MODE, typename AT>
__global__ __launch_bounds__(256) void gemm128K(
    const AT* __restrict__ A, const bf16_t* __restrict__ WT,
    bf16_t* __restrict__ out,
    const float* __restrict__ colBias,
    const float* __restrict__ bnMean, const float* __restrict__ bnVar,
    const float* __restrict__ bnG, const float* __restrict__ bnB,
    const float* __restrict__ dinv, int nrows)
{
    __shared__ __align__(16) bf16_t As[64 * 136];
    __shared__ __align__(16) bf16_t Bs[128 * 136];
    int tid = threadIdx.x;
    int rb = blockIdx.x * 64;

    {
        const uint4* src = (const uint4*)WT;
        uint4* dst = (uint4*)Bs;
        for (int i = tid; i < (128 * 136 * 2) / 16; i += 256) dst[i] = src[i];
    }
    if constexpr (sizeof(AT) == 4) {
        for (int it = 0; it < 8; ++it) {
            int flat = it * 1024 + tid * 4;
            int r = flat >> 7, c = flat & 127;
            int row = rb + r;
            float4 v;
            if (row < nrows) v = ((const float4*)A)[row * 32 + (c >> 2)];
            else             v = make_float4(0.f, 0.f, 0.f, 0.f);
            bf16x4 w4;
            w4.x = (bf16_t)v.x; w4.y = (bf16_t)v.y; w4.z = (bf16_t)v.z; w4.w = (bf16_t)v.w;
            *(bf16x4*)&As[r * 136 + c] = w4;
        }
    } else {
        for (int it = 0; it < 4; ++it) {
            int flat = it * 2048 + tid * 8;
            int r = flat >> 7, c = flat & 127;
            int row = rb + r;
            bf16x8 v = (bf16x8)(bf16_t)0.f;
            if (row < nrows) v = ((const bf16x8*)A)[row * 16 + (c >> 3)];
            *(bf16x8*)&As[r * 136 + c] = v;
        }
    }
    __syncthreads();

    int lane = tid & 63;
    int wid = tid >> 6;
    int m = lane & 15, q = lane >> 4;

    f32x4 acc[8];
#pragma unroll
    for (int c = 0; c < 8; ++c) acc[c] = (f32x4){0.f, 0.f, 0.f, 0.f};

    const bf16_t* aRow = &As[(wid * 16 + m) * 136 + q * 8];
#pragma unroll
    for (int kk = 0; kk < 4; ++kk) {
        bf16x8 af = *(const bf16x8*)(aRow + kk * 32);
#pragma unroll
        for (int c = 0; c < 8; ++c) {
            bf16x8 bfr = *(const bf16x8*)&Bs[(c * 16 + m) * 136 + q * 8 + kk * 32];
            acc[c] = __builtin_amdgcn_mfma_f32_16x16x32_bf16(af, bfr, acc[c], 0, 0, 0);
        }
    }

    int r0 = rb + wid * 16 + q * 4;
    float dv[4];
    if (MODE == 1) {
#pragma unroll
        for (int i = 0; i < 4; ++i) dv[i] = (r0 + i < nrows) ? dinv[r0 + i] : 0.f;
    }
#pragma unroll
    for (int c = 0; c < 8; ++c) {
        int j = c * 16 + m;
        float cb = 0.f, scale = 1.f, shift = 0.f;
        if (MODE == 0) {
            cb = colBias[j];
            float rs = rsqrtf(bnVar[j] + EPS_BN);
            scale = bnG[j] * rs;
            shift = bnB[j] - bnMean[j] * scale;
        } else if (MODE == 2) {
            cb = colBias[j];
        }
#pragma unroll
        for (int i = 0; i < 4; ++i) {
            int r = r0 + i;
            if (r < nrows) {
                float v = acc[c][i];
                if (MODE == 0) { v = (v + cb) * scale + shift; v = fmaxf(v, 0.f); }
                else if (MODE == 1) { v = v * dv[i]; }
                else { v = v + cb; }
                out[r * 128 + j] = (bf16_t)v;
            }
        }
    }
}

// ---------------- aggregation (half-wave per node, src-sorted rows) ----------------

template <int RELU, int RES>
__global__ __launch_bounds__(256) void aggK(
    const uint2* __restrict__ ts, const unsigned* __restrict__ slots,
    const int* __restrict__ cnt, const float* __restrict__ dinv,
    const float4* __restrict__ bias, const uint2* __restrict__ residual,
    uint2* __restrict__ out,
    const uint2* __restrict__ ov, const int* __restrict__ ovCnt, int n)
{
    int tid = threadIdx.x;
    int node = blockIdx.x * 8 + (tid >> 5);
    int hl = tid & 31;          // lane within half-wave
    int hb = tid & 32;          // base lane of my half within the wave
    if (node >= n) return;
    int nb = node << 5;

    uint2 sv = ts[nb | hl];     // self-loop term
    float a0 = blo(sv.x), a1 = bhi(sv.x), a2 = blo(sv.y), a3 = bhi(sv.y);

    int c = min(cnt[node], SLOTS);
    unsigned my = slots[nb | hl];   // sorted ascending by src

    int j = 0;
    for (; j + 3 < c; j += 4) {
        unsigned p0 = __shfl(my, hb | j);
        unsigned p1 = __shfl(my, hb | (j + 1));
        unsigned p2 = __shfl(my, hb | (j + 2));
        unsigned p3 = __shfl(my, hb | (j + 3));
        uint2 v0 = ts[((p0 >> 15) << 5) | hl];
        uint2 v1 = ts[((p1 >> 15) << 5) | hl];
        uint2 v2 = ts[((p2 >> 15) << 5) | hl];
        uint2 v3 = ts[((p3 >> 15) << 5) | hl];
        float w0 = (float)(p0 & 32767u) * WINV;
        float w1 = (float)(p1 & 32767u) * WINV;
        float w2 = (float)(p2 & 32767u) * WINV;
        float w3 = (float)(p3 & 32767u) * WINV;
        a0 += w0 * blo(v0.x) + w1 * blo(v1.x) + w2 * blo(v2.x) + w3 * blo(v3.x);
        a1 += w0 * bhi(v0.x) + w1 * bhi(v1.x) + w2 * bhi(v2.x) + w3 * bhi(v3.x);
        a2 += w0 * blo(v0.y) + w1 * blo(v1.y) + w2 * blo(v2.y) + w3 * blo(v3.y);
        a3 += w0 * bhi(v0.y) + w1 * bhi(v1.y) + w2 * bhi(v2.y) + w3 * bhi(v3.y);
    }
    for (; j < c; ++j) {
        unsigned p0 = __shfl(my, hb | j);
        uint2 v0 = ts[((p0 >> 15) << 5) | hl];
        float w0 = (float)(p0 & 32767u) * WINV;
        a0 += w0 * blo(v0.x);
        a1 += w0 * bhi(v0.x);
        a2 += w0 * blo(v0.y);
        a3 += w0 * bhi(v0.y);
    }
    int no = *ovCnt;
    for (int k = 0; k < no; ++k) {
        uint2 o = ov[k];
        if ((int)o.x == node) {
            uint2 v = ts[((o.y >> 15) << 5) | hl];
            float w = (float)(o.y & 32767u) * WINV;
            a0 += w * blo(v.x);
            a1 += w * bhi(v.x);
            a2 += w * blo(v.y);
            a3 += w * bhi(v.y);
        }
    }

    float di = dinv[node];
    float4 bb = bias[hl];
    float r0 = a0 * di + bb.x;
    float r1 = a1 * di + bb.y;
    float r2 = a2 * di + bb.z;
    float r3 = a3 * di + bb.w;
    if (RES) {
        uint2 rr = residual[nb | hl];
        r0 += blo(rr.x); r1 += bhi(rr.x); r2 += blo(rr.y); r3 += bhi(rr.y);
    }
    if (RELU) {
        r0 = fmaxf(r0, 0.f); r1 = fmaxf(r1, 0.f);
        r2 = fmaxf(r2, 0.f); r3 = fmaxf(r3, 0.f);
    }
    bf16x4 o4;
    o4.x = (bf16_t)r0; o4.y = (bf16_t)r1; o4.z = (bf16_t)r2; o4.w = (bf16_t)r3;
    out[nb | hl] = *(uint2*)&o4;
}

// ---------------- final: LayerNorm -> ReLU -> Linear(128->3) ----------------

__global__ __launch_bounds__(256) void finalK(
    const bf16_t* __restrict__ Z, const float* __restrict__ g,
    const float* __restrict__ b, const float* __restrict__ Wc2,
    const float* __restrict__ bc2, float* __restrict__ out, int n)
{
    int node = blockIdx.x * 4 + (threadIdx.x >> 6);
    int lane = threadIdx.x & 63;
    if (node >= n) return;
    bf16x2 z2 = ((const bf16x2*)Z)[(node << 6) + lane];
    float zx0 = (float)z2.x, zy0 = (float)z2.y;
    float s1 = zx0 + zy0;
    float s2 = zx0 * zx0 + zy0 * zy0;
    for (int off = 1; off < 64; off <<= 1) {
        s1 += __shfl_xor(s1, off);
        s2 += __shfl_xor(s2, off);
    }
    float mu = s1 * (1.f / 128.f);
    float var = s2 * (1.f / 128.f) - mu * mu;
    float rstd = rsqrtf(var + EPS_LN);
    float zx = fmaxf((zx0 - mu) * rstd * g[2 * lane] + b[2 * lane], 0.f);
    float zy = fmaxf((zy0 - mu) * rstd * g[2 * lane + 1] + b[2 * lane + 1], 0.f);
    float p0 = zx * Wc2[(2 * lane) * 3 + 0] + zy * Wc2[(2 * lane + 1) * 3 + 0];
    float p1 = zx * Wc2[(2 * lane) * 3 + 1] + zy * Wc2[(2 * lane + 1) * 3 + 1];
    float p2 = zx * Wc2[(2 * lane) * 3 + 2] + zy * Wc2[(2 * lane + 1) * 3 + 2];
    for (int off = 1; off < 64; off <<= 1) {
        p0 += __shfl_xor(p0, off);
        p1 += __shfl_xor(p1, off);
        p2 += __shfl_xor(p2, off);
    }
    if (lane == 0) {
        out[node * 3 + 0] = p0 + bc2[0];
        out[node * 3 + 1] = p1 + bc2[1];
        out[node * 3 + 2] = p2 + bc2[2];
    }
}

// ---------------- launch ----------------

extern "C" void kernel_launch(void* const* d_in, const int* in_sizes, int n_in,
                              void* d_out, int out_size, void* d_ws, size_t ws_size,
                              hipStream_t stream) {
    const float* x      = (const float*)d_in[0];
    const int*   ei     = (const int*)d_in[1];
    const float* ea     = (const float*)d_in[2];
    const float* W_pre  = (const float*)d_in[3];
    const float* b_pre  = (const float*)d_in[4];
    const float* bn_g   = (const float*)d_in[5];
    const float* bn_b   = (const float*)d_in[6];
    const float* bn_m   = (const float*)d_in[7];
    const float* bn_v   = (const float*)d_in[8];
    const float* W1     = (const float*)d_in[9];
    const float* b1     = (const float*)d_in[10];
    const float* W2     = (const float*)d_in[11];
    const float* b2     = (const float*)d_in[12];
    const float* Wc1    = (const float*)d_in[13];
    const float* bc1    = (const float*)d_in[14];
    const float* ln_g   = (const float*)d_in[15];
    const float* ln_b   = (const float*)d_in[16];
    const float* Wc2    = (const float*)d_in[17];
    const float* bc2    = (const float*)d_in[18];
    float* outp = (float*)d_out;

    const int N = in_sizes[0] / 128;
    const int E = in_sizes[2];

    char* p = (char*)d_ws;
    auto alloc = [&](size_t bytes) -> void* {
        void* r = (void*)p;
        p += (bytes + 255) & ~(size_t)255;
        return r;
    };
    bf16_t*   h0    = (bf16_t*)alloc((size_t)N * 128 * 2);
    bf16_t*   bufA  = (bf16_t*)alloc((size_t)N * 128 * 2);
    bf16_t*   bufB  = (bf16_t*)alloc((size_t)N * 128 * 2);
    float*    dinv  = (float*)alloc((size_t)N * 4);
    int*      cnt   = (int*)alloc((size_t)N * 4);
    int*      ovCnt = (int*)alloc(256);
    uint2*    ov    = (uint2*)alloc((size_t)4096 * 8);
    unsigned* slots = (unsigned*)alloc((size_t)N * SLOTS * 4);
    bf16_t*   WT    = (bf16_t*)alloc((size_t)4 * 128 * 136 * 2);

    bf16_t* WT_pre = WT + 0 * 128 * 136;
    bf16_t* WT_1   = WT + 1 * 128 * 136;
    bf16_t* WT_2   = WT + 2 * 128 * 136;
    bf16_t* WT_c1  = WT + 3 * 128 * 136;

    int gE = (E + 255) / 256;
    int gG = (N + 63) / 64;
    int gW = (N + 3) / 4;
    int gH = (N + 7) / 8;

    hipMemsetAsync(cnt, 0, (size_t)N * 4, stream);
    hipMemsetAsync(ovCnt, 0, 4, stream);

    convertAllK<<<256, 256, 0, stream>>>(W_pre, W1, W2, Wc1, WT);

    // adjacency fill: NPASS dst-range passes so the scatter region is L2-resident
    int range = (N + NPASS - 1) / NPASS;
    for (int ps = 0; ps < NPASS; ++ps) {
        int lo = ps * range;
        int hi = min(N, lo + range);
        fillPassK<<<gE, 256, 0, stream>>>(ei, ea, cnt, slots, ov, ovCnt, E, lo, hi);
    }
    degDinvSortK<<<gH, 256, 0, stream>>>(slots, cnt, ov, ovCnt, dinv, N);

    // h0 = relu(bn(x@W_pre + b_pre))
    gemm128K<0, float><<<gG, 256, 0, stream>>>(x, WT_pre, h0, b_pre, bn_m, bn_v, bn_g, bn_b, nullptr, N);
    // conv1
    gemm128K<1, bf16_t><<<gG, 256, 0, stream>>>(h0, WT_1, bufA, nullptr, nullptr, nullptr, nullptr, nullptr, dinv, N);
    aggK<1, 0><<<gH, 256, 0, stream>>>((const uint2*)bufA, slots, cnt, dinv, (const float4*)b1,
                                       nullptr, (uint2*)bufB, ov, ovCnt, N);
    // conv2 (+residual h0)
    gemm128K<1, bf16_t><<<gG, 256, 0, stream>>>(bufB, WT_2, bufA, nullptr, nullptr, nullptr, nullptr, nullptr, dinv, N);
    aggK<0, 1><<<gH, 256, 0, stream>>>((const uint2*)bufA, slots, cnt, dinv, (const float4*)b2,
                                       (const uint2*)h0, (uint2*)bufB, ov, ovCnt, N);
    // z = h@Wc1 + bc1
    gemm128K<2, bf16_t><<<gG, 256, 0, stream>>>(bufB, WT_c1, bufA, bc1, nullptr, nullptr, nullptr, nullptr, nullptr, N);
    // out = relu(LN(z)) @ Wc2 + bc2
    finalK<<<gW, 256, 0, stream>>>(bufA, ln_g, ln_b, Wc2, bc2, outp, N);
}

// Round 6
// 492.882 us; speedup vs baseline: 1.1048x; 1.0800x over previous
//
#include <hip/hip_runtime.h>
#include <hip/hip_bf16.h>

typedef __bf16 bf16_t;
typedef bf16_t bf16x8 __attribute__((ext_vector_type(8)));
typedef bf16_t bf16x4 __attribute__((ext_vector_type(4)));
typedef bf16_t bf16x2 __attribute__((ext_vector_type(2)));
typedef float f32x4 __attribute__((ext_vector_type(4)));
typedef float f32x2 __attribute__((ext_vector_type(2)));

#define EPS_BN 1e-5f
#define EPS_LN 1e-5f
#define SLOTS 32
#define NPASS 4
#define WSCALE 32767.f
#define WINV (1.f / 32767.f)

__device__ __forceinline__ float blo(unsigned u) { return __uint_as_float(u << 16); }
__device__ __forceinline__ float bhi(unsigned u) { return __uint_as_float(u & 0xFFFF0000u); }
__device__ __forceinline__ f32x2 f8lo(unsigned u) { return __builtin_amdgcn_cvt_pk_f32_fp8((int)u, false); }
__device__ __forceinline__ f32x2 f8hi(unsigned u) { return __builtin_amdgcn_cvt_pk_f32_fp8((int)u, true); }

// ---------------- weight convert: 4x W[i][o] fp32 -> WT[o*136+i] bf16 (padded) ----------------

__global__ void convertAllK(const float* __restrict__ W0, const float* __restrict__ W1,
                            const float* __restrict__ W2, const float* __restrict__ W3,
                            bf16_t* __restrict__ WT) {
    int flat = blockIdx.x * 256 + threadIdx.x;   // 0..65535
    int which = flat >> 14, r = flat & 16383;
    const float* W = (which == 0) ? W0 : (which == 1) ? W1 : (which == 2) ? W2 : W3;
    int i = r >> 7, o = r & 127;
    WT[which * 128 * 136 + o * 136 + i] = (bf16_t)W[r];
}

// ---------------- adjacency fill, one dst-range pass (L2-resident scatter) ----------------
// slot entry: (src << 15) | round(w * 32767), w in [0,1)

__global__ __launch_bounds__(256) void fillPassK(
    const int* __restrict__ ei, const float* __restrict__ ea,
    int* __restrict__ cnt, unsigned* __restrict__ slots,
    uint2* __restrict__ ov, int* __restrict__ ovCnt, int E, int lo, int hi)
{
    int e = blockIdx.x * 256 + threadIdx.x;
    if (e >= E) return;
    int d = ei[E + e];          // edge_index[1][e]
    if (d < lo || d >= hi) return;
    int s = ei[e];              // edge_index[0][e]
    unsigned wq = __float2uint_rn(ea[e] * WSCALE);
    unsigned pk = ((unsigned)s << 15) | wq;
    int pos = atomicAdd(&cnt[d], 1);
    if (pos < SLOTS) {
        slots[(d << 5) + pos] = pk;
    } else {
        int o = atomicAdd(ovCnt, 1);
        ov[o] = make_uint2((unsigned)d, pk);
    }
}

// dinv = rsqrt(1 + sum w)
__global__ __launch_bounds__(256) void degDinvK(
    const unsigned* __restrict__ slots, const int* __restrict__ cnt,
    const uint2* __restrict__ ov, const int* __restrict__ ovCnt,
    float* __restrict__ dinv, int n)
{
    int tid = threadIdx.x;
    int node = blockIdx.x * 8 + (tid >> 5);
    int hl = tid & 31;
    if (node >= n) return;
    int c = min(cnt[node], SLOTS);
    float w = 0.f;
    if (hl < c) w = (float)(slots[(node << 5) + hl] & 32767u) * WINV;
    for (int off = 1; off < 32; off <<= 1) w += __shfl_xor(w, off);
    int no = *ovCnt;
    for (int k = 0; k < no; ++k) {
        uint2 o = ov[k];
        if ((int)o.x == node) w += (float)(o.y & 32767u) * WINV;
    }
    if (hl == 0) dinv[node] = rsqrtf(fmaxf(1.f + w, 1e-12f));
}

// ---------------- GEMM: out[r][j] = epilogue( sum_k A[r][k]*W[k][j] ) ----------------
// MODE 0: BN(acc + colBias) then ReLU -> bf16   (input preprocess, A fp32)
// MODE 1: acc * dinv[row] -> fp8 e4m3           (conv message; B cols permuted for packed stores)
// MODE 2: acc + colBias -> bf16                 (classifier linear 1, A bf16)
// Each block stages B once and processes 2 row-tiles of 64.

template <int MODE, typename AT>
__global__ __launch_bounds__(256) void gemm128K(
    const AT* __restrict__ A, const bf16_t* __restrict__ WT,
    bf16_t* __restrict__ outb, unsigned* __restrict__ out8,
    const float* __restrict__ colBias,
    const float* __restrict__ bnMean, const float* __restrict__ bnVar,
    const float* __restrict__ bnG, const float* __restrict__ bnB,
    const float* __restrict__ dinv, int nrows)
{
    __shared__ __align__(16) bf16_t As[64 * 136];
    __shared__ __align__(16) bf16_t Bs[128 * 136];
    int tid = threadIdx.x;
    int rb0 = blockIdx.x * 128;

    // stage WT into LDS. MODE 1: permute rows so LDS slot o holds true column
    // sigma(o) = (o&15)*8 + (o>>4)  => lane m's 8 c-accumulators are consecutive features.
    {
        const uint4* src = (const uint4*)WT;
        uint4* dst = (uint4*)Bs;
        if (MODE == 1) {
            for (int i = tid; i < 128 * 17; i += 256) {
                int row = i / 17, k = i - row * 17;
                int so = ((row & 15) << 3) | (row >> 4);
                dst[row * 17 + k] = src[so * 17 + k];
            }
        } else {
            for (int i = tid; i < 128 * 17; i += 256) dst[i] = src[i];
        }
    }

    int lane = tid & 63;
    int wid = tid >> 6;
    int m = lane & 15, q = lane >> 4;

    for (int t = 0; t < 2; ++t) {
        int rb = rb0 + t * 64;
        if (rb >= nrows) break;
        if (t) __syncthreads();    // protect As before restage
        // stage A tile (64 rows x 128 cols -> bf16, padded stride 136)
        if constexpr (sizeof(AT) == 4) {
            for (int it = 0; it < 8; ++it) {
                int flat = it * 1024 + tid * 4;
                int r = flat >> 7, c = flat & 127;
                int row = rb + r;
                float4 v;
                if (row < nrows) v = ((const float4*)A)[row * 32 + (c >> 2)];
                else             v = make_float4(0.f, 0.f, 0.f, 0.f);
                bf16x4 w4;
                w4.x = (bf16_t)v.x; w4.y = (bf16_t)v.y; w4.z = (bf16_t)v.z; w4.w = (bf16_t)v.w;
                *(bf16x4*)&As[r * 136 + c] = w4;
            }
        } else {
            for (int it = 0; it < 4; ++it) {
                int flat = it * 2048 + tid * 8;
                int r = flat >> 7, c = flat & 127;
                int row = rb + r;
                bf16x8 v = (bf16x8)(bf16_t)0.f;
                if (row < nrows) v = ((const bf16x8*)A)[row * 16 + (c >> 3)];
                *(bf16x8*)&As[r * 136 + c] = v;
            }
        }
        __syncthreads();

        f32x4 acc[8];
#pragma unroll
        for (int c = 0; c < 8; ++c) acc[c] = (f32x4){0.f, 0.f, 0.f, 0.f};

        const bf16_t* aRow = &As[(wid * 16 + m) * 136 + q * 8];
#pragma unroll
        for (int kk = 0; kk < 4; ++kk) {
            bf16x8 af = *(const bf16x8*)(aRow + kk * 32);
#pragma unroll
            for (int c = 0; c < 8; ++c) {
                bf16x8 bfr = *(const bf16x8*)&Bs[(c * 16 + m) * 136 + q * 8 + kk * 32];
                acc[c] = __builtin_amdgcn_mfma_f32_16x16x32_bf16(af, bfr, acc[c], 0, 0, 0);
            }
        }

        int r0 = rb + wid * 16 + q * 4;
        if (MODE == 1) {
            float dv[4];
#pragma unroll
            for (int i = 0; i < 4; ++i) dv[i] = (r0 + i < nrows) ? dinv[r0 + i] : 0.f;
#pragma unroll
            for (int i = 0; i < 4; ++i) {
                int r = r0 + i;
                if (r < nrows) {
                    float v0 = acc[0][i] * dv[i], v1 = acc[1][i] * dv[i];
                    float v2 = acc[2][i] * dv[i], v3 = acc[3][i] * dv[i];
                    float v4 = acc[4][i] * dv[i], v5 = acc[5][i] * dv[i];
                    float v6 = acc[6][i] * dv[i], v7 = acc[7][i] * dv[i];
                    int lo = __builtin_amdgcn_cvt_pk_fp8_f32(v0, v1, 0, false);
                    lo = __builtin_amdgcn_cvt_pk_fp8_f32(v2, v3, lo, true);
                    int hi = __builtin_amdgcn_cvt_pk_fp8_f32(v4, v5, 0, false);
                    hi = __builtin_amdgcn_cvt_pk_fp8_f32(v6, v7, hi, true);
                    // row r, features m*8..m*8+7 -> bytes r*128 + m*8
                    ((uint2*)out8)[(r << 4) | m] = make_uint2((unsigned)lo, (unsigned)hi);
                }
            }
        } else {
#pragma unroll
            for (int c = 0; c < 8; ++c) {
                int j = c * 16 + m;
                float cb = 0.f, scale = 1.f, shift = 0.f;
                if (MODE == 0) {
                    cb = colBias[j];
                    float rs = rsqrtf(bnVar[j] + EPS_BN);
                    scale = bnG[j] * rs;
                    shift = bnB[j] - bnMean[j] * scale;
                } else {
                    cb = colBias[j];
                }
#pragma unroll
                for (int i = 0; i < 4; ++i) {
                    int r = r0 + i;
                    if (r < nrows) {
                        float v = acc[c][i];
                        if (MODE == 0) { v = (v + cb) * scale + shift; v = fmaxf(v, 0.f); }
                        else { v = v + cb; }
                        outb[r * 128 + j] = (bf16_t)v;
                    }
                }
            }
        }
    }
}

// ---------------- aggregation (half-wave per node, fp8 message table) ----------------
// out[d] = act(dinv[d]*(ts[d] + sum w*ts[src]) + b (+res)); ts rows = 128 B fp8.

template <int RELU, int RES>
__global__ __launch_bounds__(256) void aggK(
    const unsigned* __restrict__ ts8, const unsigned* __restrict__ slots,
    const int* __restrict__ cnt, const float* __restrict__ dinv,
    const float4* __restrict__ bias, const uint2* __restrict__ residual,
    uint2* __restrict__ out,
    const uint2* __restrict__ ov, const int* __restrict__ ovCnt, int n)
{
    int tid = threadIdx.x;
    int node = blockIdx.x * 8 + (tid >> 5);
    int hl = tid & 31;          // lane within half-wave
    int hb = tid & 32;          // base lane of my half within the wave
    if (node >= n) return;
    int nb = node << 5;

    unsigned su = ts8[nb | hl]; // self-loop term: features 4hl..4hl+3
    f32x2 sl = f8lo(su), sh = f8hi(su);
    float a0 = sl.x, a1 = sl.y, a2 = sh.x, a3 = sh.y;

    int c = min(cnt[node], SLOTS);
    unsigned my = slots[nb | hl];

    int j = 0;
    for (; j + 3 < c; j += 4) {
        unsigned p0 = __shfl(my, hb | j);
        unsigned p1 = __shfl(my, hb | (j + 1));
        unsigned p2 = __shfl(my, hb | (j + 2));
        unsigned p3 = __shfl(my, hb | (j + 3));
        unsigned u0 = ts8[((p0 >> 15) << 5) | hl];
        unsigned u1 = ts8[((p1 >> 15) << 5) | hl];
        unsigned u2 = ts8[((p2 >> 15) << 5) | hl];
        unsigned u3 = ts8[((p3 >> 15) << 5) | hl];
        float w0 = (float)(p0 & 32767u) * WINV;
        float w1 = (float)(p1 & 32767u) * WINV;
        float w2 = (float)(p2 & 32767u) * WINV;
        float w3 = (float)(p3 & 32767u) * WINV;
        f32x2 l0 = f8lo(u0), h0_ = f8hi(u0);
        f32x2 l1 = f8lo(u1), h1_ = f8hi(u1);
        f32x2 l2 = f8lo(u2), h2_ = f8hi(u2);
        f32x2 l3 = f8lo(u3), h3_ = f8hi(u3);
        a0 += w0 * l0.x + w1 * l1.x + w2 * l2.x + w3 * l3.x;
        a1 += w0 * l0.y + w1 * l1.y + w2 * l2.y + w3 * l3.y;
        a2 += w0 * h0_.x + w1 * h1_.x + w2 * h2_.x + w3 * h3_.x;
        a3 += w0 * h0_.y + w1 * h1_.y + w2 * h2_.y + w3 * h3_.y;
    }
    for (; j < c; ++j) {
        unsigned p0 = __shfl(my, hb | j);
        unsigned u0 = ts8[((p0 >> 15) << 5) | hl];
        float w0 = (float)(p0 & 32767u) * WINV;
        f32x2 l0 = f8lo(u0), h0_ = f8hi(u0);
        a0 += w0 * l0.x;
        a1 += w0 * l0.y;
        a2 += w0 * h0_.x;
        a3 += w0 * h0_.y;
    }
    int no = *ovCnt;
    for (int k = 0; k < no; ++k) {
        uint2 o = ov[k];
        if ((int)o.x == node) {
            unsigned u = ts8[((o.y >> 15) << 5) | hl];
            float w = (float)(o.y & 32767u) * WINV;
            f32x2 l = f8lo(u), h_ = f8hi(u);
            a0 += w * l.x;
            a1 += w * l.y;
            a2 += w * h_.x;
            a3 += w * h_.y;
        }
    }

    float di = dinv[node];
    float4 bb = bias[hl];
    float r0 = a0 * di + bb.x;
    float r1 = a1 * di + bb.y;
    float r2 = a2 * di + bb.z;
    float r3 = a3 * di + bb.w;
    if (RES) {
        uint2 rr = residual[nb | hl];
        r0 += blo(rr.x); r1 += bhi(rr.x); r2 += blo(rr.y); r3 += bhi(rr.y);
    }
    if (RELU) {
        r0 = fmaxf(r0, 0.f); r1 = fmaxf(r1, 0.f);
        r2 = fmaxf(r2, 0.f); r3 = fmaxf(r3, 0.f);
    }
    bf16x4 o4;
    o4.x = (bf16_t)r0; o4.y = (bf16_t)r1; o4.z = (bf16_t)r2; o4.w = (bf16_t)r3;
    out[nb | hl] = *(uint2*)&o4;
}

// ---------------- final: LayerNorm -> ReLU -> Linear(128->3) ----------------

__global__ __launch_bounds__(256) void finalK(
    const bf16_t* __restrict__ Z, const float* __restrict__ g,
    const float* __restrict__ b, const float* __restrict__ Wc2,
    const float* __restrict__ bc2, float* __restrict__ out, int n)
{
    int node = blockIdx.x * 4 + (threadIdx.x >> 6);
    int lane = threadIdx.x & 63;
    if (node >= n) return;
    bf16x2 z2 = ((const bf16x2*)Z)[(node << 6) + lane];
    float zx0 = (float)z2.x, zy0 = (float)z2.y;
    float s1 = zx0 + zy0;
    float s2 = zx0 * zx0 + zy0 * zy0;
    for (int off = 1; off < 64; off <<= 1) {
        s1 += __shfl_xor(s1, off);
        s2 += __shfl_xor(s2, off);
    }
    float mu = s1 * (1.f / 128.f);
    float var = s2 * (1.f / 128.f) - mu * mu;
    float rstd = rsqrtf(var + EPS_LN);
    float zx = fmaxf((zx0 - mu) * rstd * g[2 * lane] + b[2 * lane], 0.f);
    float zy = fmaxf((zy0 - mu) * rstd * g[2 * lane + 1] + b[2 * lane + 1], 0.f);
    float p0 = zx * Wc2[(2 * lane) * 3 + 0] + zy * Wc2[(2 * lane + 1) * 3 + 0];
    float p1 = zx * Wc2[(2 * lane) * 3 + 1] + zy * Wc2[(2 * lane + 1) * 3 + 1];
    float p2 = zx * Wc2[(2 * lane) * 3 + 2] + zy * Wc2[(2 * lane + 1) * 3 + 2];
    for (int off = 1; off < 64; off <<= 1) {
        p0 += __shfl_xor(p0, off);
        p1 += __shfl_xor(p1, off);
        p2 += __shfl_xor(p2, off);
    }
    if (lane == 0) {
        out[node * 3 + 0] = p0 + bc2[0];
        out[node * 3 + 1] = p1 + bc2[1];
        out[node * 3 + 2] = p2 + bc2[2];
    }
}

// ---------------- launch ----------------

extern "C" void kernel_launch(void* const* d_in, const int* in_sizes, int n_in,
                              void* d_out, int out_size, void* d_ws, size_t ws_size,
                              hipStream_t stream) {
    const float* x      = (const float*)d_in[0];
    const int*   ei     = (const int*)d_in[1];
    const float* ea     = (const float*)d_in[2];
    const float* W_pre  = (const float*)d_in[3];
    const float* b_pre  = (const float*)d_in[4];
    const float* bn_g   = (const float*)d_in[5];
    const float* bn_b   = (const float*)d_in[6];
    const float* bn_m   = (const float*)d_in[7];
    const float* bn_v   = (const float*)d_in[8];
    const float* W1     = (const float*)d_in[9];
    const float* b1     = (const float*)d_in[10];
    const float* W2     = (const float*)d_in[11];
    const float* b2     = (const float*)d_in[12];
    const float* Wc1    = (const float*)d_in[13];
    const float* bc1    = (const float*)d_in[14];
    const float* ln_g   = (const float*)d_in[15];
    const float* ln_b   = (const float*)d_in[16];
    const float* Wc2    = (const float*)d_in[17];
    const float* bc2    = (const float*)d_in[18];
    float* outp = (float*)d_out;

    const int N = in_sizes[0] / 128;
    const int E = in_sizes[2];

    char* p = (char*)d_ws;
    auto alloc = [&](size_t bytes) -> void* {
        void* r = (void*)p;
        p += (bytes + 255) & ~(size_t)255;
        return r;
    };
    bf16_t*   h0    = (bf16_t*)alloc((size_t)N * 128 * 2);
    bf16_t*   bufA  = (bf16_t*)alloc((size_t)N * 128 * 2);
    bf16_t*   bufB  = (bf16_t*)alloc((size_t)N * 128 * 2);
    unsigned* ts8   = (unsigned*)alloc((size_t)N * 128);
    float*    dinv  = (float*)alloc((size_t)N * 4);
    int*      cnt   = (int*)alloc((size_t)N * 4);
    int*      ovCnt = (int*)alloc(256);
    uint2*    ov    = (uint2*)alloc((size_t)4096 * 8);
    unsigned* slots = (unsigned*)alloc((size_t)N * SLOTS * 4);
    bf16_t*   WT    = (bf16_t*)alloc((size_t)4 * 128 * 136 * 2);

    bf16_t* WT_pre = WT + 0 * 128 * 136;
    bf16_t* WT_1   = WT + 1 * 128 * 136;
    bf16_t* WT_2   = WT + 2 * 128 * 136;
    bf16_t* WT_c1  = WT + 3 * 128 * 136;

    int gE = (E + 255) / 256;
    int gG2 = (N + 127) / 128;
    int gW = (N + 3) / 4;
    int gH = (N + 7) / 8;

    hipMemsetAsync(cnt, 0, (size_t)N * 4, stream);
    hipMemsetAsync(ovCnt, 0, 4, stream);

    convertAllK<<<256, 256, 0, stream>>>(W_pre, W1, W2, Wc1, WT);

    // adjacency fill: NPASS dst-range passes so the scatter region is L2-resident
    int range = (N + NPASS - 1) / NPASS;
    for (int ps = 0; ps < NPASS; ++ps) {
        int lo = ps * range;
        int hi = min(N, lo + range);
        fillPassK<<<gE, 256, 0, stream>>>(ei, ea, cnt, slots, ov, ovCnt, E, lo, hi);
    }
    degDinvK<<<gH, 256, 0, stream>>>(slots, cnt, ov, ovCnt, dinv, N);

    // h0 = relu(bn(x@W_pre + b_pre))
    gemm128K<0, float><<<gG2, 256, 0, stream>>>(x, WT_pre, h0, nullptr, b_pre, bn_m, bn_v, bn_g, bn_b, nullptr, N);
    // conv1: ts8 = fp8(dinv * (h0@W1))
    gemm128K<1, bf16_t><<<gG2, 256, 0, stream>>>(h0, WT_1, nullptr, ts8, nullptr, nullptr, nullptr, nullptr, nullptr, dinv, N);
    aggK<1, 0><<<gH, 256, 0, stream>>>(ts8, slots, cnt, dinv, (const float4*)b1,
                                       nullptr, (uint2*)bufB, ov, ovCnt, N);
    // conv2 (+residual h0)
    gemm128K<1, bf16_t><<<gG2, 256, 0, stream>>>(bufB, WT_2, nullptr, ts8, nullptr, nullptr, nullptr, nullptr, nullptr, dinv, N);
    aggK<0, 1><<<gH, 256, 0, stream>>>(ts8, slots, cnt, dinv, (const float4*)b2,
                                       (const uint2*)h0, (uint2*)bufB, ov, ovCnt, N);
    // z = h@Wc1 + bc1
    gemm128K<2, bf16_t><<<gG2, 256, 0, stream>>>(bufB, WT_c1, bufA, nullptr, bc1, nullptr, nullptr, nullptr, nullptr, nullptr, N);
    // out = relu(LN(z)) @ Wc2 + bc2
    finalK<<<gW, 256, 0, stream>>>(bufA, ln_g, ln_b, Wc2, bc2, outp, N);
}

// Round 7
// 448.772 us; speedup vs baseline: 1.2133x; 1.0983x over previous
//
#include <hip/hip_runtime.h>
#include <hip/hip_bf16.h>

typedef __bf16 bf16_t;
typedef bf16_t bf16x8 __attribute__((ext_vector_type(8)));
typedef bf16_t bf16x4 __attribute__((ext_vector_type(4)));
typedef bf16_t bf16x2 __attribute__((ext_vector_type(2)));
typedef float f32x4 __attribute__((ext_vector_type(4)));
typedef float f32x2 __attribute__((ext_vector_type(2)));

#define EPS_BN 1e-5f
#define EPS_LN 1e-5f
#define SLOTS 32
#define NPASS 4
#define WSCALE 32767.f
#define WINV (1.f / 32767.f)

__device__ __forceinline__ float blo(unsigned u) { return __uint_as_float(u << 16); }
__device__ __forceinline__ float bhi(unsigned u) { return __uint_as_float(u & 0xFFFF0000u); }
__device__ __forceinline__ f32x2 f8lo(unsigned u) { return __builtin_amdgcn_cvt_pk_f32_fp8((int)u, false); }
__device__ __forceinline__ f32x2 f8hi(unsigned u) { return __builtin_amdgcn_cvt_pk_f32_fp8((int)u, true); }

// ---------------- weight convert: 4x W[i][o] fp32 -> WT[o*136+i] bf16 (padded) ----------------

__global__ void convertAllK(const float* __restrict__ W0, const float* __restrict__ W1,
                            const float* __restrict__ W2, const float* __restrict__ W3,
                            bf16_t* __restrict__ WT) {
    int flat = blockIdx.x * 256 + threadIdx.x;   // 0..65535
    int which = flat >> 14, r = flat & 16383;
    const float* W = (which == 0) ? W0 : (which == 1) ? W1 : (which == 2) ? W2 : W3;
    int i = r >> 7, o = r & 127;
    WT[which * 128 * 136 + o * 136 + i] = (bf16_t)W[r];
}

// ---------------- adjacency fill, one dst-range pass (L2-resident scatter) ----------------
// slot entry: (src << 15) | round(w * 32767), w in [0,1)

__global__ __launch_bounds__(256) void fillPassK(
    const int* __restrict__ ei, const float* __restrict__ ea,
    int* __restrict__ cnt, unsigned* __restrict__ slots,
    uint2* __restrict__ ov, int* __restrict__ ovCnt, int E, int lo, int hi)
{
    int e = blockIdx.x * 256 + threadIdx.x;
    if (e >= E) return;
    int d = ei[E + e];          // edge_index[1][e]
    if (d < lo || d >= hi) return;
    int s = ei[e];              // edge_index[0][e]
    unsigned wq = __float2uint_rn(ea[e] * WSCALE);
    unsigned pk = ((unsigned)s << 15) | wq;
    int pos = atomicAdd(&cnt[d], 1);
    if (pos < SLOTS) {
        slots[(d << 5) + pos] = pk;
    } else {
        int o = atomicAdd(ovCnt, 1);
        ov[o] = make_uint2((unsigned)d, pk);
    }
}

// dinv = rsqrt(1 + sum w)
__global__ __launch_bounds__(256) void degDinvK(
    const unsigned* __restrict__ slots, const int* __restrict__ cnt,
    const uint2* __restrict__ ov, const int* __restrict__ ovCnt,
    float* __restrict__ dinv, int n)
{
    int tid = threadIdx.x;
    int node = blockIdx.x * 8 + (tid >> 5);
    int hl = tid & 31;
    if (node >= n) return;
    int c = min(cnt[node], SLOTS);
    float w = 0.f;
    if (hl < c) w = (float)(slots[(node << 5) + hl] & 32767u) * WINV;
    for (int off = 1; off < 32; off <<= 1) w += __shfl_xor(w, off);
    int no = *ovCnt;
    for (int k = 0; k < no; ++k) {
        uint2 o = ov[k];
        if ((int)o.x == node) w += (float)(o.y & 32767u) * WINV;
    }
    if (hl == 0) dinv[node] = rsqrtf(fmaxf(1.f + w, 1e-12f));
}

// ---------------- GEMM: out[r][j] = epilogue( sum_k A[r][k]*W[k][j] ) ----------------
// A fragments are loaded DIRECTLY global->registers (each A element is consumed by
// exactly one lane: row = wid*16 + (lane&15), k-block = lane>>4). LDS holds only B.
// MODE 0: BN(acc + colBias) then ReLU -> bf16   (input preprocess, A fp32)
// MODE 1: acc * dinv[row] -> fp8 e4m3           (conv message; B cols permuted for packed stores)
// MODE 2: acc + colBias -> bf16                 (classifier linear 1, A bf16)

template <int MODE, typename AT>
__global__ __launch_bounds__(256) void gemm128K(
    const AT* __restrict__ A, const bf16_t* __restrict__ WT,
    bf16_t* __restrict__ outb, unsigned* __restrict__ out8,
    const float* __restrict__ colBias,
    const float* __restrict__ bnMean, const float* __restrict__ bnVar,
    const float* __restrict__ bnG, const float* __restrict__ bnB,
    const float* __restrict__ dinv, int nrows)
{
    __shared__ __align__(16) bf16_t Bs[128 * 136];   // 34816 B
    int tid = threadIdx.x;
    int rb = blockIdx.x * 64;

    // stage WT into LDS. MODE 1: permute rows so LDS slot o holds true column
    // sigma(o) = (o&15)*8 + (o>>4)  => lane m's 8 c-accumulators are consecutive features.
    {
        const uint4* src = (const uint4*)WT;
        uint4* dst = (uint4*)Bs;
        if (MODE == 1) {
            for (int i = tid; i < 128 * 17; i += 256) {
                int row = i / 17, k = i - row * 17;
                int so = ((row & 15) << 3) | (row >> 4);
                dst[row * 17 + k] = src[so * 17 + k];
            }
        } else {
            for (int i = tid; i < 128 * 17; i += 256) dst[i] = src[i];
        }
    }

    int lane = tid & 63;
    int wid = tid >> 6;
    int m = lane & 15, q = lane >> 4;
    int myRow = rb + wid * 16 + m;
    int rowL = min(myRow, nrows - 1);

    // A fragments: af[kk] = A[rowL][q*8 + kk*32 .. +8]  (16 B each, no LDS round trip)
    bf16x8 af[4];
    if constexpr (sizeof(AT) == 4) {
#pragma unroll
        for (int kk = 0; kk < 4; ++kk) {
            float4 v0 = ((const float4*)A)[rowL * 32 + q * 2 + kk * 8];
            float4 v1 = ((const float4*)A)[rowL * 32 + q * 2 + kk * 8 + 1];
            bf16x8 w8;
            w8[0] = (bf16_t)v0.x; w8[1] = (bf16_t)v0.y; w8[2] = (bf16_t)v0.z; w8[3] = (bf16_t)v0.w;
            w8[4] = (bf16_t)v1.x; w8[5] = (bf16_t)v1.y; w8[6] = (bf16_t)v1.z; w8[7] = (bf16_t)v1.w;
            af[kk] = w8;
        }
    } else {
#pragma unroll
        for (int kk = 0; kk < 4; ++kk)
            af[kk] = ((const bf16x8*)A)[rowL * 16 + q + kk * 4];
    }

    __syncthreads();   // Bs ready

    f32x4 acc[8];
#pragma unroll
    for (int c = 0; c < 8; ++c) acc[c] = (f32x4){0.f, 0.f, 0.f, 0.f};

#pragma unroll
    for (int kk = 0; kk < 4; ++kk) {
#pragma unroll
        for (int c = 0; c < 8; ++c) {
            bf16x8 bfr = *(const bf16x8*)&Bs[(c * 16 + m) * 136 + q * 8 + kk * 32];
            acc[c] = __builtin_amdgcn_mfma_f32_16x16x32_bf16(af[kk], bfr, acc[c], 0, 0, 0);
        }
    }

    int r0 = rb + wid * 16 + q * 4;
    if (MODE == 1) {
        float dv[4];
#pragma unroll
        for (int i = 0; i < 4; ++i) dv[i] = (r0 + i < nrows) ? dinv[r0 + i] : 0.f;
#pragma unroll
        for (int i = 0; i < 4; ++i) {
            int r = r0 + i;
            if (r < nrows) {
                float v0 = acc[0][i] * dv[i], v1 = acc[1][i] * dv[i];
                float v2 = acc[2][i] * dv[i], v3 = acc[3][i] * dv[i];
                float v4 = acc[4][i] * dv[i], v5 = acc[5][i] * dv[i];
                float v6 = acc[6][i] * dv[i], v7 = acc[7][i] * dv[i];
                int lo = __builtin_amdgcn_cvt_pk_fp8_f32(v0, v1, 0, false);
                lo = __builtin_amdgcn_cvt_pk_fp8_f32(v2, v3, lo, true);
                int hi = __builtin_amdgcn_cvt_pk_fp8_f32(v4, v5, 0, false);
                hi = __builtin_amdgcn_cvt_pk_fp8_f32(v6, v7, hi, true);
                ((uint2*)out8)[(r << 4) | m] = make_uint2((unsigned)lo, (unsigned)hi);
            }
        }
    } else {
#pragma unroll
        for (int c = 0; c < 8; ++c) {
            int j = c * 16 + m;
            float cb = colBias[j], scale = 1.f, shift = 0.f;
            if (MODE == 0) {
                float rs = rsqrtf(bnVar[j] + EPS_BN);
                scale = bnG[j] * rs;
                shift = bnB[j] - bnMean[j] * scale;
            }
#pragma unroll
            for (int i = 0; i < 4; ++i) {
                int r = r0 + i;
                if (r < nrows) {
                    float v = acc[c][i];
                    if (MODE == 0) { v = (v + cb) * scale + shift; v = fmaxf(v, 0.f); }
                    else { v = v + cb; }
                    outb[r * 128 + j] = (bf16_t)v;
                }
            }
        }
    }
}

// ---------------- aggregation (half-wave per node, fp8 message table) ----------------
// out[d] = act(dinv[d]*(ts[d] + sum w*ts[src]) + b (+res)); ts rows = 128 B fp8.
// Weights/offsets pre-decoded once per lane; packed f32x2 accumulate.

template <int RELU, int RES>
__global__ __launch_bounds__(256) void aggK(
    const unsigned* __restrict__ ts8, const unsigned* __restrict__ slots,
    const int* __restrict__ cnt, const float* __restrict__ dinv,
    const float4* __restrict__ bias, const uint2* __restrict__ residual,
    uint2* __restrict__ out,
    const uint2* __restrict__ ov, const int* __restrict__ ovCnt, int n)
{
    int tid = threadIdx.x;
    int node = blockIdx.x * 8 + (tid >> 5);
    int hl = tid & 31;          // lane within half-wave
    int hb = tid & 32;          // base lane of my half within the wave
    if (node >= n) return;
    int nb = node << 5;

    unsigned su = ts8[nb | hl]; // self-loop term: features 4hl..4hl+3
    f32x2 a01 = f8lo(su), a23 = f8hi(su);

    int c = min(cnt[node], SLOTS);
    unsigned my = slots[nb | hl];
    float myw = (float)(my & 32767u) * WINV;    // decode once per lane
    int myoff = (int)(my >> 15) << 5;           // uint-index base of src row

    int j = 0;
    for (; j + 3 < c; j += 4) {
        int o0 = __shfl(myoff, hb | j);
        int o1 = __shfl(myoff, hb | (j + 1));
        int o2 = __shfl(myoff, hb | (j + 2));
        int o3 = __shfl(myoff, hb | (j + 3));
        float w0 = __shfl(myw, hb | j);
        float w1 = __shfl(myw, hb | (j + 1));
        float w2 = __shfl(myw, hb | (j + 2));
        float w3 = __shfl(myw, hb | (j + 3));
        unsigned u0 = ts8[o0 | hl];
        unsigned u1 = ts8[o1 | hl];
        unsigned u2 = ts8[o2 | hl];
        unsigned u3 = ts8[o3 | hl];
        f32x2 W0 = (f32x2){w0, w0}, W1 = (f32x2){w1, w1};
        f32x2 W2 = (f32x2){w2, w2}, W3 = (f32x2){w3, w3};
        a01 += W0 * f8lo(u0) + W1 * f8lo(u1) + W2 * f8lo(u2) + W3 * f8lo(u3);
        a23 += W0 * f8hi(u0) + W1 * f8hi(u1) + W2 * f8hi(u2) + W3 * f8hi(u3);
    }
    for (; j < c; ++j) {
        int o0 = __shfl(myoff, hb | j);
        float w0 = __shfl(myw, hb | j);
        unsigned u0 = ts8[o0 | hl];
        f32x2 W0 = (f32x2){w0, w0};
        a01 += W0 * f8lo(u0);
        a23 += W0 * f8hi(u0);
    }
    int no = *ovCnt;
    for (int k = 0; k < no; ++k) {
        uint2 o = ov[k];
        if ((int)o.x == node) {
            unsigned u = ts8[(int)(o.y >> 15 << 5) | hl];
            float w = (float)(o.y & 32767u) * WINV;
            f32x2 W = (f32x2){w, w};
            a01 += W * f8lo(u);
            a23 += W * f8hi(u);
        }
    }

    float di = dinv[node];
    float4 bb = bias[hl];
    float r0 = a01.x * di + bb.x;
    float r1 = a01.y * di + bb.y;
    float r2 = a23.x * di + bb.z;
    float r3 = a23.y * di + bb.w;
    if (RES) {
        uint2 rr = residual[nb | hl];
        r0 += blo(rr.x); r1 += bhi(rr.x); r2 += blo(rr.y); r3 += bhi(rr.y);
    }
    if (RELU) {
        r0 = fmaxf(r0, 0.f); r1 = fmaxf(r1, 0.f);
        r2 = fmaxf(r2, 0.f); r3 = fmaxf(r3, 0.f);
    }
    bf16x4 o4;
    o4.x = (bf16_t)r0; o4.y = (bf16_t)r1; o4.z = (bf16_t)r2; o4.w = (bf16_t)r3;
    out[nb | hl] = *(uint2*)&o4;
}

// ---------------- final: LayerNorm -> ReLU -> Linear(128->3) ----------------

__global__ __launch_bounds__(256) void finalK(
    const bf16_t* __restrict__ Z, const float* __restrict__ g,
    const float* __restrict__ b, const float* __restrict__ Wc2,
    const float* __restrict__ bc2, float* __restrict__ out, int n)
{
    int node = blockIdx.x * 4 + (threadIdx.x >> 6);
    int lane = threadIdx.x & 63;
    if (node >= n) return;
    bf16x2 z2 = ((const bf16x2*)Z)[(node << 6) + lane];
    float zx0 = (float)z2.x, zy0 = (float)z2.y;
    float s1 = zx0 + zy0;
    float s2 = zx0 * zx0 + zy0 * zy0;
    for (int off = 1; off < 64; off <<= 1) {
        s1 += __shfl_xor(s1, off);
        s2 += __shfl_xor(s2, off);
    }
    float mu = s1 * (1.f / 128.f);
    float var = s2 * (1.f / 128.f) - mu * mu;
    float rstd = rsqrtf(var + EPS_LN);
    float zx = fmaxf((zx0 - mu) * rstd * g[2 * lane] + b[2 * lane], 0.f);
    float zy = fmaxf((zy0 - mu) * rstd * g[2 * lane + 1] + b[2 * lane + 1], 0.f);
    float p0 = zx * Wc2[(2 * lane) * 3 + 0] + zy * Wc2[(2 * lane + 1) * 3 + 0];
    float p1 = zx * Wc2[(2 * lane) * 3 + 1] + zy * Wc2[(2 * lane + 1) * 3 + 1];
    float p2 = zx * Wc2[(2 * lane) * 3 + 2] + zy * Wc2[(2 * lane + 1) * 3 + 2];
    for (int off = 1; off < 64; off <<= 1) {
        p0 += __shfl_xor(p0, off);
        p1 += __shfl_xor(p1, off);
        p2 += __shfl_xor(p2, off);
    }
    if (lane == 0) {
        out[node * 3 + 0] = p0 + bc2[0];
        out[node * 3 + 1] = p1 + bc2[1];
        out[node * 3 + 2] = p2 + bc2[2];
    }
}

// ---------------- launch ----------------

extern "C" void kernel_launch(void* const* d_in, const int* in_sizes, int n_in,
                              void* d_out, int out_size, void* d_ws, size_t ws_size,
                              hipStream_t stream) {
    const float* x      = (const float*)d_in[0];
    const int*   ei     = (const int*)d_in[1];
    const float* ea     = (const float*)d_in[2];
    const float* W_pre  = (const float*)d_in[3];
    const float* b_pre  = (const float*)d_in[4];
    const float* bn_g   = (const float*)d_in[5];
    const float* bn_b   = (const float*)d_in[6];
    const float* bn_m   = (const float*)d_in[7];
    const float* bn_v   = (const float*)d_in[8];
    const float* W1     = (const float*)d_in[9];
    const float* b1     = (const float*)d_in[10];
    const float* W2     = (const float*)d_in[11];
    const float* b2     = (const float*)d_in[12];
    const float* Wc1    = (const float*)d_in[13];
    const float* bc1    = (const float*)d_in[14];
    const float* ln_g   = (const float*)d_in[15];
    const float* ln_b   = (const float*)d_in[16];
    const float* Wc2    = (const float*)d_in[17];
    const float* bc2    = (const float*)d_in[18];
    float* outp = (float*)d_out;

    const int N = in_sizes[0] / 128;
    const int E = in_sizes[2];

    char* p = (char*)d_ws;
    auto alloc = [&](size_t bytes) -> void* {
        void* r = (void*)p;
        p += (bytes + 255) & ~(size_t)255;
        return r;
    };
    bf16_t*   h0    = (bf16_t*)alloc((size_t)N * 128 * 2);
    bf16_t*   bufA  = (bf16_t*)alloc((size_t)N * 128 * 2);
    bf16_t*   bufB  = (bf16_t*)alloc((size_t)N * 128 * 2);
    unsigned* ts8   = (unsigned*)alloc((size_t)N * 128);
    float*    dinv  = (float*)alloc((size_t)N * 4);
    int*      cnt   = (int*)alloc((size_t)N * 4);
    int*      ovCnt = (int*)alloc(256);
    uint2*    ov    = (uint2*)alloc((size_t)4096 * 8);
    unsigned* slots = (unsigned*)alloc((size_t)N * SLOTS * 4);
    bf16_t*   WT    = (bf16_t*)alloc((size_t)4 * 128 * 136 * 2);

    bf16_t* WT_pre = WT + 0 * 128 * 136;
    bf16_t* WT_1   = WT + 1 * 128 * 136;
    bf16_t* WT_2   = WT + 2 * 128 * 136;
    bf16_t* WT_c1  = WT + 3 * 128 * 136;

    int gE = (E + 255) / 256;
    int gG = (N + 63) / 64;
    int gW = (N + 3) / 4;
    int gH = (N + 7) / 8;

    hipMemsetAsync(cnt, 0, (size_t)N * 4, stream);
    hipMemsetAsync(ovCnt, 0, 4, stream);

    convertAllK<<<256, 256, 0, stream>>>(W_pre, W1, W2, Wc1, WT);

    // adjacency fill: NPASS dst-range passes so the scatter region is L2-resident
    int range = (N + NPASS - 1) / NPASS;
    for (int ps = 0; ps < NPASS; ++ps) {
        int lo = ps * range;
        int hi = min(N, lo + range);
        fillPassK<<<gE, 256, 0, stream>>>(ei, ea, cnt, slots, ov, ovCnt, E, lo, hi);
    }
    degDinvK<<<gH, 256, 0, stream>>>(slots, cnt, ov, ovCnt, dinv, N);

    // h0 = relu(bn(x@W_pre + b_pre))
    gemm128K<0, float><<<gG, 256, 0, stream>>>(x, WT_pre, h0, nullptr, b_pre, bn_m, bn_v, bn_g, bn_b, nullptr, N);
    // conv1: ts8 = fp8(dinv * (h0@W1))
    gemm128K<1, bf16_t><<<gG, 256, 0, stream>>>(h0, WT_1, nullptr, ts8, nullptr, nullptr, nullptr, nullptr, nullptr, dinv, N);
    aggK<1, 0><<<gH, 256, 0, stream>>>(ts8, slots, cnt, dinv, (const float4*)b1,
                                       nullptr, (uint2*)bufB, ov, ovCnt, N);
    // conv2 (+residual h0)
    gemm128K<1, bf16_t><<<gG, 256, 0, stream>>>(bufB, WT_2, nullptr, ts8, nullptr, nullptr, nullptr, nullptr, nullptr, dinv, N);
    aggK<0, 1><<<gH, 256, 0, stream>>>(ts8, slots, cnt, dinv, (const float4*)b2,
                                       (const uint2*)h0, (uint2*)bufB, ov, ovCnt, N);
    // z = h@Wc1 + bc1
    gemm128K<2, bf16_t><<<gG, 256, 0, stream>>>(bufB, WT_c1, bufA, nullptr, bc1, nullptr, nullptr, nullptr, nullptr, nullptr, N);
    // out = relu(LN(z)) @ Wc2 + bc2
    finalK<<<gW, 256, 0, stream>>>(bufA, ln_g, ln_b, Wc2, bc2, outp, N);
}

// Round 8
// 412.472 us; speedup vs baseline: 1.3201x; 1.0880x over previous
//
#include <hip/hip_runtime.h>
#include <hip/hip_bf16.h>

typedef __bf16 bf16_t;
typedef bf16_t bf16x8 __attribute__((ext_vector_type(8)));
typedef bf16_t bf16x4 __attribute__((ext_vector_type(4)));
typedef float f32x4 __attribute__((ext_vector_type(4)));
typedef float f32x2 __attribute__((ext_vector_type(2)));

#define EPS_BN 1e-5f
#define EPS_LN 1e-5f
#define SLOTS 32
#define NPASS 4
#define WSCALE 32767.f
#define WINV (1.f / 32767.f)

__device__ __forceinline__ float blo(unsigned u) { return __uint_as_float(u << 16); }
__device__ __forceinline__ float bhi(unsigned u) { return __uint_as_float(u & 0xFFFF0000u); }
__device__ __forceinline__ f32x2 f8lo(unsigned u) { return __builtin_amdgcn_cvt_pk_f32_fp8((int)u, false); }
__device__ __forceinline__ f32x2 f8hi(unsigned u) { return __builtin_amdgcn_cvt_pk_f32_fp8((int)u, true); }

// ---------------- prep: zero cnt/ovCnt + convert 4x W[i][o] fp32 -> WT[o*136+i] bf16 ----------------

__global__ void prepK(const float* __restrict__ W0, const float* __restrict__ W1,
                      const float* __restrict__ W2, const float* __restrict__ W3,
                      bf16_t* __restrict__ WT, int* __restrict__ cnt,
                      int* __restrict__ ovCnt, int n) {
    int flat = blockIdx.x * 256 + threadIdx.x;
    if (flat < n) cnt[flat] = 0;
    if (flat == 0) *ovCnt = 0;
    if (flat < 65536) {
        int which = flat >> 14, r = flat & 16383;
        const float* W = (which == 0) ? W0 : (which == 1) ? W1 : (which == 2) ? W2 : W3;
        int i = r >> 7, o = r & 127;
        WT[which * 128 * 136 + o * 136 + i] = (bf16_t)W[r];
    }
}

// ---------------- adjacency fill, one dst-range pass (L2-resident scatter) ----------------
// slot entry: (src << 15) | round(w * 32767), w in [0,1)

__global__ __launch_bounds__(256) void fillPassK(
    const int* __restrict__ ei, const float* __restrict__ ea,
    int* __restrict__ cnt, unsigned* __restrict__ slots,
    uint2* __restrict__ ov, int* __restrict__ ovCnt, int E, int lo, int hi)
{
    int e = blockIdx.x * 256 + threadIdx.x;
    if (e >= E) return;
    int d = ei[E + e];          // edge_index[1][e]
    if (d < lo || d >= hi) return;
    int s = ei[e];              // edge_index[0][e]
    unsigned wq = __float2uint_rn(ea[e] * WSCALE);
    unsigned pk = ((unsigned)s << 15) | wq;
    int pos = atomicAdd(&cnt[d], 1);
    if (pos < SLOTS) {
        slots[(d << 5) + pos] = pk;
    } else {
        int o = atomicAdd(ovCnt, 1);
        ov[o] = make_uint2((unsigned)d, pk);
    }
}

// dinv = rsqrt(1 + sum w)
__global__ __launch_bounds__(256) void degDinvK(
    const unsigned* __restrict__ slots, const int* __restrict__ cnt,
    const uint2* __restrict__ ov, const int* __restrict__ ovCnt,
    float* __restrict__ dinv, int n)
{
    int tid = threadIdx.x;
    int node = blockIdx.x * 8 + (tid >> 5);
    int hl = tid & 31;
    if (node >= n) return;
    int c = min(cnt[node], SLOTS);
    float w = 0.f;
    if (hl < c) w = (float)(slots[(node << 5) + hl] & 32767u) * WINV;
    for (int off = 1; off < 32; off <<= 1) w += __shfl_xor(w, off);
    int no = *ovCnt;
    for (int k = 0; k < no; ++k) {
        uint2 o = ov[k];
        if ((int)o.x == node) w += (float)(o.y & 32767u) * WINV;
    }
    if (hl == 0) dinv[node] = rsqrtf(fmaxf(1.f + w, 1e-12f));
}

// ---------------- GEMM: out[r][j] = epilogue( sum_k A[r][k]*W[k][j] ) ----------------
// A fragments loaded directly global->registers; LDS holds only B.
// MODE 0: BN(acc + colBias) then ReLU -> bf16   (input preprocess, A fp32)
// MODE 1: acc * dinv[row] -> fp8 e4m3           (conv message; B cols permuted for packed stores)

template <int MODE, typename AT>
__global__ __launch_bounds__(256) void gemm128K(
    const AT* __restrict__ A, const bf16_t* __restrict__ WT,
    bf16_t* __restrict__ outb, unsigned* __restrict__ out8,
    const float* __restrict__ colBias,
    const float* __restrict__ bnMean, const float* __restrict__ bnVar,
    const float* __restrict__ bnG, const float* __restrict__ bnB,
    const float* __restrict__ dinv, int nrows)
{
    __shared__ __align__(16) bf16_t Bs[128 * 136];   // 34816 B
    int tid = threadIdx.x;
    int rb = blockIdx.x * 64;

    {
        const uint4* src = (const uint4*)WT;
        uint4* dst = (uint4*)Bs;
        if (MODE == 1) {
            for (int i = tid; i < 128 * 17; i += 256) {
                int row = i / 17, k = i - row * 17;
                int so = ((row & 15) << 3) | (row >> 4);
                dst[row * 17 + k] = src[so * 17 + k];
            }
        } else {
            for (int i = tid; i < 128 * 17; i += 256) dst[i] = src[i];
        }
    }

    int lane = tid & 63;
    int wid = tid >> 6;
    int m = lane & 15, q = lane >> 4;
    int myRow = rb + wid * 16 + m;
    int rowL = min(myRow, nrows - 1);

    bf16x8 af[4];
    if constexpr (sizeof(AT) == 4) {
#pragma unroll
        for (int kk = 0; kk < 4; ++kk) {
            float4 v0 = ((const float4*)A)[rowL * 32 + q * 2 + kk * 8];
            float4 v1 = ((const float4*)A)[rowL * 32 + q * 2 + kk * 8 + 1];
            bf16x8 w8;
            w8[0] = (bf16_t)v0.x; w8[1] = (bf16_t)v0.y; w8[2] = (bf16_t)v0.z; w8[3] = (bf16_t)v0.w;
            w8[4] = (bf16_t)v1.x; w8[5] = (bf16_t)v1.y; w8[6] = (bf16_t)v1.z; w8[7] = (bf16_t)v1.w;
            af[kk] = w8;
        }
    } else {
#pragma unroll
        for (int kk = 0; kk < 4; ++kk)
            af[kk] = ((const bf16x8*)A)[rowL * 16 + q + kk * 4];
    }

    __syncthreads();

    f32x4 acc[8];
#pragma unroll
    for (int c = 0; c < 8; ++c) acc[c] = (f32x4){0.f, 0.f, 0.f, 0.f};

#pragma unroll
    for (int kk = 0; kk < 4; ++kk) {
#pragma unroll
        for (int c = 0; c < 8; ++c) {
            bf16x8 bfr = *(const bf16x8*)&Bs[(c * 16 + m) * 136 + q * 8 + kk * 32];
            acc[c] = __builtin_amdgcn_mfma_f32_16x16x32_bf16(af[kk], bfr, acc[c], 0, 0, 0);
        }
    }

    int r0 = rb + wid * 16 + q * 4;
    if (MODE == 1) {
        float dv[4];
#pragma unroll
        for (int i = 0; i < 4; ++i) dv[i] = (r0 + i < nrows) ? dinv[r0 + i] : 0.f;
#pragma unroll
        for (int i = 0; i < 4; ++i) {
            int r = r0 + i;
            if (r < nrows) {
                float v0 = acc[0][i] * dv[i], v1 = acc[1][i] * dv[i];
                float v2 = acc[2][i] * dv[i], v3 = acc[3][i] * dv[i];
                float v4 = acc[4][i] * dv[i], v5 = acc[5][i] * dv[i];
                float v6 = acc[6][i] * dv[i], v7 = acc[7][i] * dv[i];
                int lo = __builtin_amdgcn_cvt_pk_fp8_f32(v0, v1, 0, false);
                lo = __builtin_amdgcn_cvt_pk_fp8_f32(v2, v3, lo, true);
                int hi = __builtin_amdgcn_cvt_pk_fp8_f32(v4, v5, 0, false);
                hi = __builtin_amdgcn_cvt_pk_fp8_f32(v6, v7, hi, true);
                ((uint2*)out8)[(r << 4) | m] = make_uint2((unsigned)lo, (unsigned)hi);
            }
        }
    } else {
#pragma unroll
        for (int c = 0; c < 8; ++c) {
            int j = c * 16 + m;
            float cb = colBias[j];
            float rs = rsqrtf(bnVar[j] + EPS_BN);
            float scale = bnG[j] * rs;
            float shift = bnB[j] - bnMean[j] * scale;
#pragma unroll
            for (int i = 0; i < 4; ++i) {
                int r = r0 + i;
                if (r < nrows) {
                    float v = (acc[c][i] + cb) * scale + shift;
                    outb[r * 128 + j] = (bf16_t)fmaxf(v, 0.f);
                }
            }
        }
    }
}

// ---------------- aggregation (half-wave per node, wide fp8 gather) ----------------
// lane layout within half-wave: slot = hl>>3 (4 edge slots), f = hl&7 (16-feature chunk).
// one load instruction fetches 4 edge rows (512 B / wave-half-pair).

template <int RELU, int RES>
__global__ __launch_bounds__(256) void aggK(
    const uint4* __restrict__ ts16, const unsigned* __restrict__ slots,
    const int* __restrict__ cnt, const float* __restrict__ dinv,
    const float4* __restrict__ bias, const uint4* __restrict__ residual,
    uint4* __restrict__ out,
    const uint2* __restrict__ ov, const int* __restrict__ ovCnt, int n)
{
    int tid = threadIdx.x;
    int node = blockIdx.x * 8 + (tid >> 5);
    int hl = tid & 31;
    int hb = tid & 32;
    if (node >= n) return;
    int slot = hl >> 3;
    int f = hl & 7;
    int nb = node << 5;

    int c = min(cnt[node], SLOTS);
    unsigned my = slots[nb | hl];
    float myw = (float)(my & 32767u) * WINV;
    int myoff = (int)(my >> 15) << 3;     // uint4 units: src*8

    f32x2 acc[8];
#pragma unroll
    for (int k = 0; k < 8; ++k) acc[k] = (f32x2){0.f, 0.f};

    for (int j = 0; j < c; j += 8) {
        int e0 = j + slot, e1 = j + 4 + slot;
        int s0 = hb + min(e0, 31), s1 = hb + min(e1, 31);
        int o0 = __shfl(myoff, s0);
        int o1 = __shfl(myoff, s1);
        float w0 = __shfl(myw, s0);
        float w1 = __shfl(myw, s1);
        bool v0 = e0 < c, v1 = e1 < c;
        uint4 u0 = make_uint4(0u, 0u, 0u, 0u), u1 = make_uint4(0u, 0u, 0u, 0u);
        if (v0) u0 = ts16[o0 + f];
        if (v1) u1 = ts16[o1 + f];
        if (!v0) w0 = 0.f;
        if (!v1) w1 = 0.f;
        f32x2 W0 = (f32x2){w0, w0}, W1 = (f32x2){w1, w1};
        acc[0] += W0 * f8lo(u0.x) + W1 * f8lo(u1.x);
        acc[1] += W0 * f8hi(u0.x) + W1 * f8hi(u1.x);
        acc[2] += W0 * f8lo(u0.y) + W1 * f8lo(u1.y);
        acc[3] += W0 * f8hi(u0.y) + W1 * f8hi(u1.y);
        acc[4] += W0 * f8lo(u0.z) + W1 * f8lo(u1.z);
        acc[5] += W0 * f8hi(u0.z) + W1 * f8hi(u1.z);
        acc[6] += W0 * f8lo(u0.w) + W1 * f8lo(u1.w);
        acc[7] += W0 * f8hi(u0.w) + W1 * f8hi(u1.w);
    }

    // overflow edges (rare): slot-0 lanes only, so reduction counts them once
    int no = *ovCnt;
    for (int k = 0; k < no; ++k) {
        uint2 o = ov[k];
        if ((int)o.x == node && slot == 0) {
            uint4 u = ts16[((int)(o.y >> 15) << 3) + f];
            float w = (float)(o.y & 32767u) * WINV;
            f32x2 W = (f32x2){w, w};
            acc[0] += W * f8lo(u.x); acc[1] += W * f8hi(u.x);
            acc[2] += W * f8lo(u.y); acc[3] += W * f8hi(u.y);
            acc[4] += W * f8lo(u.z); acc[5] += W * f8hi(u.z);
            acc[6] += W * f8lo(u.w); acc[7] += W * f8hi(u.w);
        }
    }

    // reduce across the 4 edge slots (lanes hl^8, hl^16)
#pragma unroll
    for (int k = 0; k < 8; ++k) {
        f32x2 t;
        t.x = __shfl_xor(acc[k].x, 8);  t.y = __shfl_xor(acc[k].y, 8);
        acc[k] += t;
        t.x = __shfl_xor(acc[k].x, 16); t.y = __shfl_xor(acc[k].y, 16);
        acc[k] += t;
    }

    if (slot == 0) {   // lanes hl<8 hold chunk f; do epilogue + write
        float di = dinv[node];
        // self-loop row
        uint4 su = ts16[(node << 3) + f];
        acc[0] += f8lo(su.x); acc[1] += f8hi(su.x);
        acc[2] += f8lo(su.y); acc[3] += f8hi(su.y);
        acc[4] += f8lo(su.z); acc[5] += f8hi(su.z);
        acc[6] += f8lo(su.w); acc[7] += f8hi(su.w);
        float r[16];
#pragma unroll
        for (int k = 0; k < 8; ++k) {
            float4 bb = bias[f * 4 + (k >> 1)];
            float b0 = (k & 1) ? bb.z : bb.x;
            float b1 = (k & 1) ? bb.w : bb.y;
            r[2 * k]     = acc[k].x * di + b0;
            r[2 * k + 1] = acc[k].y * di + b1;
        }
        if (RES) {
            uint4 q0 = residual[(node << 4) + f * 2];
            uint4 q1 = residual[(node << 4) + f * 2 + 1];
            r[0] += blo(q0.x);  r[1] += bhi(q0.x);
            r[2] += blo(q0.y);  r[3] += bhi(q0.y);
            r[4] += blo(q0.z);  r[5] += bhi(q0.z);
            r[6] += blo(q0.w);  r[7] += bhi(q0.w);
            r[8] += blo(q1.x);  r[9] += bhi(q1.x);
            r[10] += blo(q1.y); r[11] += bhi(q1.y);
            r[12] += blo(q1.z); r[13] += bhi(q1.z);
            r[14] += blo(q1.w); r[15] += bhi(q1.w);
        }
        if (RELU) {
#pragma unroll
            for (int k = 0; k < 16; ++k) r[k] = fmaxf(r[k], 0.f);
        }
        bf16x8 o0, o1;
#pragma unroll
        for (int k = 0; k < 8; ++k) { o0[k] = (bf16_t)r[k]; o1[k] = (bf16_t)r[8 + k]; }
        out[(node << 4) + f * 2]     = *(uint4*)&o0;
        out[(node << 4) + f * 2 + 1] = *(uint4*)&o1;
    }
}

// ---------------- classifier: z = h@Wc1 + bc1; LN; ReLU; out = z@Wc2 + bc2 ----------------

__global__ __launch_bounds__(256) void classifierK(
    const bf16_t* __restrict__ A, const bf16_t* __restrict__ WT,
    const float* __restrict__ bc1, const float* __restrict__ g,
    const float* __restrict__ b, const float* __restrict__ Wc2,
    const float* __restrict__ bc2, float* __restrict__ out, int nrows)
{
    __shared__ __align__(16) bf16_t Bs[128 * 136];
    __shared__ float sB[128], sG[128], sLb[128], sW2[384];
    int tid = threadIdx.x;
    int rb = blockIdx.x * 64;

    {
        const uint4* src = (const uint4*)WT;
        uint4* dst = (uint4*)Bs;
        for (int i = tid; i < 128 * 17; i += 256) dst[i] = src[i];
    }
    if (tid < 128) { sB[tid] = bc1[tid]; sG[tid] = g[tid]; sLb[tid] = b[tid]; }
    for (int i = tid; i < 384; i += 256) sW2[i] = Wc2[i];

    int lane = tid & 63;
    int wid = tid >> 6;
    int m = lane & 15, q = lane >> 4;
    int rowL = min(rb + wid * 16 + m, nrows - 1);

    bf16x8 af[4];
#pragma unroll
    for (int kk = 0; kk < 4; ++kk)
        af[kk] = ((const bf16x8*)A)[rowL * 16 + q + kk * 4];

    __syncthreads();

    f32x4 acc[8];
#pragma unroll
    for (int c = 0; c < 8; ++c) acc[c] = (f32x4){0.f, 0.f, 0.f, 0.f};
#pragma unroll
    for (int kk = 0; kk < 4; ++kk) {
#pragma unroll
        for (int c = 0; c < 8; ++c) {
            bf16x8 bfr = *(const bf16x8*)&Bs[(c * 16 + m) * 136 + q * 8 + kk * 32];
            acc[c] = __builtin_amdgcn_mfma_f32_16x16x32_bf16(af[kk], bfr, acc[c], 0, 0, 0);
        }
    }

    int r0 = rb + wid * 16 + q * 4;
#pragma unroll
    for (int i = 0; i < 4; ++i) {
        float s1 = 0.f, s2 = 0.f;
#pragma unroll
        for (int c = 0; c < 8; ++c) {
            float z = acc[c][i] + sB[c * 16 + m];
            acc[c][i] = z;
            s1 += z; s2 += z * z;
        }
#pragma unroll
        for (int off = 1; off < 16; off <<= 1) {
            s1 += __shfl_xor(s1, off);
            s2 += __shfl_xor(s2, off);
        }
        float mu = s1 * (1.f / 128.f);
        float var = s2 * (1.f / 128.f) - mu * mu;
        float rstd = rsqrtf(var + EPS_LN);
        float p0 = 0.f, p1 = 0.f, p2 = 0.f;
#pragma unroll
        for (int c = 0; c < 8; ++c) {
            int j = c * 16 + m;
            float zn = (acc[c][i] - mu) * rstd * sG[j] + sLb[j];
            zn = fmaxf(zn, 0.f);
            p0 += zn * sW2[j * 3 + 0];
            p1 += zn * sW2[j * 3 + 1];
            p2 += zn * sW2[j * 3 + 2];
        }
#pragma unroll
        for (int off = 1; off < 16; off <<= 1) {
            p0 += __shfl_xor(p0, off);
            p1 += __shfl_xor(p1, off);
            p2 += __shfl_xor(p2, off);
        }
        int r = r0 + i;
        if (m == 0 && r < nrows) {
            out[r * 3 + 0] = p0 + bc2[0];
            out[r * 3 + 1] = p1 + bc2[1];
            out[r * 3 + 2] = p2 + bc2[2];
        }
    }
}

// ---------------- launch ----------------

extern "C" void kernel_launch(void* const* d_in, const int* in_sizes, int n_in,
                              void* d_out, int out_size, void* d_ws, size_t ws_size,
                              hipStream_t stream) {
    const float* x      = (const float*)d_in[0];
    const int*   ei     = (const int*)d_in[1];
    const float* ea     = (const float*)d_in[2];
    const float* W_pre  = (const float*)d_in[3];
    const float* b_pre  = (const float*)d_in[4];
    const float* bn_g   = (const float*)d_in[5];
    const float* bn_b   = (const float*)d_in[6];
    const float* bn_m   = (const float*)d_in[7];
    const float* bn_v   = (const float*)d_in[8];
    const float* W1     = (const float*)d_in[9];
    const float* b1     = (const float*)d_in[10];
    const float* W2     = (const float*)d_in[11];
    const float* b2     = (const float*)d_in[12];
    const float* Wc1    = (const float*)d_in[13];
    const float* bc1    = (const float*)d_in[14];
    const float* ln_g   = (const float*)d_in[15];
    const float* ln_b   = (const float*)d_in[16];
    const float* Wc2    = (const float*)d_in[17];
    const float* bc2    = (const float*)d_in[18];
    float* outp = (float*)d_out;

    const int N = in_sizes[0] / 128;
    const int E = in_sizes[2];

    char* p = (char*)d_ws;
    auto alloc = [&](size_t bytes) -> void* {
        void* r = (void*)p;
        p += (bytes + 255) & ~(size_t)255;
        return r;
    };
    bf16_t*   h0    = (bf16_t*)alloc((size_t)N * 128 * 2);
    bf16_t*   bufB  = (bf16_t*)alloc((size_t)N * 128 * 2);
    unsigned* ts8   = (unsigned*)alloc((size_t)N * 128);
    float*    dinv  = (float*)alloc((size_t)N * 4);
    int*      cnt   = (int*)alloc((size_t)N * 4);
    int*      ovCnt = (int*)alloc(256);
    uint2*    ov    = (uint2*)alloc((size_t)4096 * 8);
    unsigned* slots = (unsigned*)alloc((size_t)N * SLOTS * 4);
    bf16_t*   WT    = (bf16_t*)alloc((size_t)4 * 128 * 136 * 2);

    bf16_t* WT_pre = WT + 0 * 128 * 136;
    bf16_t* WT_1   = WT + 1 * 128 * 136;
    bf16_t* WT_2   = WT + 2 * 128 * 136;
    bf16_t* WT_c1  = WT + 3 * 128 * 136;

    int gE = (E + 255) / 256;
    int gG = (N + 63) / 64;
    int gH = (N + 7) / 8;
    int gP = (max(N, 65536) + 255) / 256;

    prepK<<<gP, 256, 0, stream>>>(W_pre, W1, W2, Wc1, WT, cnt, ovCnt, N);

    int range = (N + NPASS - 1) / NPASS;
    for (int ps = 0; ps < NPASS; ++ps) {
        int lo = ps * range;
        int hi = min(N, lo + range);
        fillPassK<<<gE, 256, 0, stream>>>(ei, ea, cnt, slots, ov, ovCnt, E, lo, hi);
    }
    degDinvK<<<gH, 256, 0, stream>>>(slots, cnt, ov, ovCnt, dinv, N);

    // h0 = relu(bn(x@W_pre + b_pre))
    gemm128K<0, float><<<gG, 256, 0, stream>>>(x, WT_pre, h0, nullptr, b_pre, bn_m, bn_v, bn_g, bn_b, nullptr, N);
    // conv1: ts8 = fp8(dinv * (h0@W1))
    gemm128K<1, bf16_t><<<gG, 256, 0, stream>>>(h0, WT_1, nullptr, ts8, nullptr, nullptr, nullptr, nullptr, nullptr, dinv, N);
    aggK<1, 0><<<gH, 256, 0, stream>>>((const uint4*)ts8, slots, cnt, dinv, (const float4*)b1,
                                       nullptr, (uint4*)bufB, ov, ovCnt, N);
    // conv2 (+residual h0)
    gemm128K<1, bf16_t><<<gG, 256, 0, stream>>>(bufB, WT_2, nullptr, ts8, nullptr, nullptr, nullptr, nullptr, nullptr, dinv, N);
    aggK<0, 1><<<gH, 256, 0, stream>>>((const uint4*)ts8, slots, cnt, dinv, (const float4*)b2,
                                       (const uint4*)h0, (uint4*)bufB, ov, ovCnt, N);
    // classifier: out = relu(LN(h@Wc1 + bc1)) @ Wc2 + bc2
    classifierK<<<gG, 256, 0, stream>>>(bufB, WT_c1, bc1, ln_g, ln_b, Wc2, bc2, outp, N);
}

// Round 9
// 395.119 us; speedup vs baseline: 1.3781x; 1.0439x over previous
//
#include <hip/hip_runtime.h>
#include <hip/hip_bf16.h>

typedef __bf16 bf16_t;
typedef bf16_t bf16x8 __attribute__((ext_vector_type(8)));
typedef bf16_t bf16x4 __attribute__((ext_vector_type(4)));
typedef float f32x4 __attribute__((ext_vector_type(4)));
typedef float f32x2 __attribute__((ext_vector_type(2)));

#define EPS_BN 1e-5f
#define EPS_LN 1e-5f
#define SLOTS 32
#define NPASS 4
#define WSCALE 32767.f
#define WINV (1.f / 32767.f)

__device__ __forceinline__ float blo(unsigned u) { return __uint_as_float(u << 16); }
__device__ __forceinline__ float bhi(unsigned u) { return __uint_as_float(u & 0xFFFF0000u); }
__device__ __forceinline__ f32x2 f8lo(unsigned u) { return __builtin_amdgcn_cvt_pk_f32_fp8((int)u, false); }
__device__ __forceinline__ f32x2 f8hi(unsigned u) { return __builtin_amdgcn_cvt_pk_f32_fp8((int)u, true); }

// ---------------- prep: zero cnt/ovCnt + convert 4x W[i][o] fp32 -> WT[o*136+i] bf16 ----------------

__global__ void prepK(const float* __restrict__ W0, const float* __restrict__ W1,
                      const float* __restrict__ W2, const float* __restrict__ W3,
                      bf16_t* __restrict__ WT, int* __restrict__ cnt,
                      int* __restrict__ ovCnt, int n) {
    int flat = blockIdx.x * 256 + threadIdx.x;
    if (flat < n) cnt[flat] = 0;
    if (flat == 0) *ovCnt = 0;
    if (flat < 65536) {
        int which = flat >> 14, r = flat & 16383;
        const float* W = (which == 0) ? W0 : (which == 1) ? W1 : (which == 2) ? W2 : W3;
        int i = r >> 7, o = r & 127;
        WT[which * 128 * 136 + o * 136 + i] = (bf16_t)W[r];
    }
}

// ---------------- adjacency fill: all NPASS dst-range passes in ONE kernel ----------------
// pass = blockIdx.x / blocksPerPass; blocks dispatch ~in order so the scatter
// region stays phase-local (L2-resident). slot entry: (src<<15) | round(w*32767).

__global__ __launch_bounds__(256) void fillAllK(
    const int* __restrict__ ei, const float* __restrict__ ea,
    int* __restrict__ cnt, unsigned* __restrict__ slots,
    uint2* __restrict__ ov, int* __restrict__ ovCnt, int E, int bpp, int range)
{
    int pass = blockIdx.x / bpp;
    int blk = blockIdx.x - pass * bpp;
    int e = blk * 256 + threadIdx.x;
    if (e >= E) return;
    int d = ei[E + e];          // edge_index[1][e]
    int lo = pass * range, hi = lo + range;
    if (d < lo || d >= hi) return;
    int s = ei[e];              // edge_index[0][e]
    unsigned wq = __float2uint_rn(ea[e] * WSCALE);
    unsigned pk = ((unsigned)s << 15) | wq;
    int pos = atomicAdd(&cnt[d], 1);
    if (pos < SLOTS) {
        slots[(d << 5) + pos] = pk;
    } else {
        int o = atomicAdd(ovCnt, 1);
        ov[o] = make_uint2((unsigned)d, pk);
    }
}

// dinv = rsqrt(1 + sum w); pads slot rows to multiple of 8 with (self, w=0)
__global__ __launch_bounds__(256) void degDinvK(
    unsigned* __restrict__ slots, const int* __restrict__ cnt,
    const uint2* __restrict__ ov, const int* __restrict__ ovCnt,
    float* __restrict__ dinv, int n)
{
    int tid = threadIdx.x;
    int node = blockIdx.x * 8 + (tid >> 5);
    int hl = tid & 31;
    if (node >= n) return;
    int c = min(cnt[node], SLOTS);
    int c8 = (c + 7) & ~7;
    float w = 0.f;
    if (hl < c) w = (float)(slots[(node << 5) + hl] & 32767u) * WINV;
    if (hl >= c && hl < c8) slots[(node << 5) + hl] = (unsigned)node << 15;  // pad: self, w=0
    for (int off = 1; off < 32; off <<= 1) w += __shfl_xor(w, off);
    int no = *ovCnt;
    for (int k = 0; k < no; ++k) {
        uint2 o = ov[k];
        if ((int)o.x == node) w += (float)(o.y & 32767u) * WINV;
    }
    if (hl == 0) dinv[node] = rsqrtf(fmaxf(1.f + w, 1e-12f));
}

// ---------------- GEMM: out[r][j] = epilogue( sum_k A[r][k]*W[k][j] ) ----------------
// A fragments loaded directly global->registers; LDS holds only B.
// MODE 0: BN(acc + colBias) then ReLU -> bf16   (input preprocess, A fp32)
// MODE 1: acc * dinv[row] -> fp8 e4m3           (conv message; B cols permuted for packed stores)

template <int MODE, typename AT>
__global__ __launch_bounds__(256) void gemm128K(
    const AT* __restrict__ A, const bf16_t* __restrict__ WT,
    bf16_t* __restrict__ outb, unsigned* __restrict__ out8,
    const float* __restrict__ colBias,
    const float* __restrict__ bnMean, const float* __restrict__ bnVar,
    const float* __restrict__ bnG, const float* __restrict__ bnB,
    const float* __restrict__ dinv, int nrows)
{
    __shared__ __align__(16) bf16_t Bs[128 * 136];   // 34816 B
    int tid = threadIdx.x;
    int rb = blockIdx.x * 64;

    {
        const uint4* src = (const uint4*)WT;
        uint4* dst = (uint4*)Bs;
        if (MODE == 1) {
            for (int i = tid; i < 128 * 17; i += 256) {
                int row = i / 17, k = i - row * 17;
                int so = ((row & 15) << 3) | (row >> 4);
                dst[row * 17 + k] = src[so * 17 + k];
            }
        } else {
            for (int i = tid; i < 128 * 17; i += 256) dst[i] = src[i];
        }
    }

    int lane = tid & 63;
    int wid = tid >> 6;
    int m = lane & 15, q = lane >> 4;
    int myRow = rb + wid * 16 + m;
    int rowL = min(myRow, nrows - 1);

    bf16x8 af[4];
    if constexpr (sizeof(AT) == 4) {
#pragma unroll
        for (int kk = 0; kk < 4; ++kk) {
            float4 v0 = ((const float4*)A)[rowL * 32 + q * 2 + kk * 8];
            float4 v1 = ((const float4*)A)[rowL * 32 + q * 2 + kk * 8 + 1];
            bf16x8 w8;
            w8[0] = (bf16_t)v0.x; w8[1] = (bf16_t)v0.y; w8[2] = (bf16_t)v0.z; w8[3] = (bf16_t)v0.w;
            w8[4] = (bf16_t)v1.x; w8[5] = (bf16_t)v1.y; w8[6] = (bf16_t)v1.z; w8[7] = (bf16_t)v1.w;
            af[kk] = w8;
        }
    } else {
#pragma unroll
        for (int kk = 0; kk < 4; ++kk)
            af[kk] = ((const bf16x8*)A)[rowL * 16 + q + kk * 4];
    }

    __syncthreads();

    f32x4 acc[8];
#pragma unroll
    for (int c = 0; c < 8; ++c) acc[c] = (f32x4){0.f, 0.f, 0.f, 0.f};

#pragma unroll
    for (int kk = 0; kk < 4; ++kk) {
#pragma unroll
        for (int c = 0; c < 8; ++c) {
            bf16x8 bfr = *(const bf16x8*)&Bs[(c * 16 + m) * 136 + q * 8 + kk * 32];
            acc[c] = __builtin_amdgcn_mfma_f32_16x16x32_bf16(af[kk], bfr, acc[c], 0, 0, 0);
        }
    }

    int r0 = rb + wid * 16 + q * 4;
    if (MODE == 1) {
        float dv[4];
#pragma unroll
        for (int i = 0; i < 4; ++i) dv[i] = (r0 + i < nrows) ? dinv[r0 + i] : 0.f;
#pragma unroll
        for (int i = 0; i < 4; ++i) {
            int r = r0 + i;
            if (r < nrows) {
                float v0 = acc[0][i] * dv[i], v1 = acc[1][i] * dv[i];
                float v2 = acc[2][i] * dv[i], v3 = acc[3][i] * dv[i];
                float v4 = acc[4][i] * dv[i], v5 = acc[5][i] * dv[i];
                float v6 = acc[6][i] * dv[i], v7 = acc[7][i] * dv[i];
                int lo = __builtin_amdgcn_cvt_pk_fp8_f32(v0, v1, 0, false);
                lo = __builtin_amdgcn_cvt_pk_fp8_f32(v2, v3, lo, true);
                int hi = __builtin_amdgcn_cvt_pk_fp8_f32(v4, v5, 0, false);
                hi = __builtin_amdgcn_cvt_pk_fp8_f32(v6, v7, hi, true);
                ((uint2*)out8)[(r << 4) | m] = make_uint2((unsigned)lo, (unsigned)hi);
            }
        }
    } else {
#pragma unroll
        for (int c = 0; c < 8; ++c) {
            int j = c * 16 + m;
            float cb = colBias[j];
            float rs = rsqrtf(bnVar[j] + EPS_BN);
            float scale = bnG[j] * rs;
            float shift = bnB[j] - bnMean[j] * scale;
#pragma unroll
            for (int i = 0; i < 4; ++i) {
                int r = r0 + i;
                if (r < nrows) {
                    float v = (acc[c][i] + cb) * scale + shift;
                    outb[r * 128 + j] = (bf16_t)fmaxf(v, 0.f);
                }
            }
        }
    }
}

// ---------------- aggregation (half-wave per node, wide fp8 gather, branchless) ----------------
// lane layout within half-wave: slot = hl>>3 (4 edge slots), f = hl&7 (16-feature chunk).
// slot rows are padded to c8 (multiple of 8) with (self, w=0): no predication in the loop.

template <int RELU, int RES>
__global__ __launch_bounds__(256) void aggK(
    const uint4* __restrict__ ts16, const unsigned* __restrict__ slots,
    const int* __restrict__ cnt, const float* __restrict__ dinv,
    const float4* __restrict__ bias, const uint4* __restrict__ residual,
    uint4* __restrict__ out,
    const uint2* __restrict__ ov, const int* __restrict__ ovCnt, int n)
{
    int tid = threadIdx.x;
    int node = blockIdx.x * 8 + (tid >> 5);
    int hl = tid & 31;
    int hb = tid & 32;
    if (node >= n) return;
    int slot = hl >> 3;
    int f = hl & 7;
    int nb = node << 5;

    int c8 = (min(cnt[node], SLOTS) + 7) & ~7;
    unsigned my = slots[nb | hl];
    float myw = (float)(my & 32767u) * WINV;
    int myoff = (int)(my >> 15) << 3;     // uint4 units: src*8

    f32x2 acc[8];
#pragma unroll
    for (int k = 0; k < 8; ++k) acc[k] = (f32x2){0.f, 0.f};

    // self-loop row folded into slot-1 lanes (weight 1), overlaps the gather loop
    if (slot == 1) {
        uint4 su = ts16[(node << 3) + f];
        acc[0] += f8lo(su.x); acc[1] += f8hi(su.x);
        acc[2] += f8lo(su.y); acc[3] += f8hi(su.y);
        acc[4] += f8lo(su.z); acc[5] += f8hi(su.z);
        acc[6] += f8lo(su.w); acc[7] += f8hi(su.w);
    }

    for (int j = 0; j < c8; j += 8) {
        int s0 = hb + j + slot;
        int s1 = s0 + 4;
        int o0 = __shfl(myoff, s0);
        int o1 = __shfl(myoff, s1);
        float w0 = __shfl(myw, s0);
        float w1 = __shfl(myw, s1);
        uint4 u0 = ts16[o0 + f];
        uint4 u1 = ts16[o1 + f];
        f32x2 W0 = (f32x2){w0, w0}, W1 = (f32x2){w1, w1};
        acc[0] += W0 * f8lo(u0.x) + W1 * f8lo(u1.x);
        acc[1] += W0 * f8hi(u0.x) + W1 * f8hi(u1.x);
        acc[2] += W0 * f8lo(u0.y) + W1 * f8lo(u1.y);
        acc[3] += W0 * f8hi(u0.y) + W1 * f8hi(u1.y);
        acc[4] += W0 * f8lo(u0.z) + W1 * f8lo(u1.z);
        acc[5] += W0 * f8hi(u0.z) + W1 * f8hi(u1.z);
        acc[6] += W0 * f8lo(u0.w) + W1 * f8lo(u1.w);
        acc[7] += W0 * f8hi(u0.w) + W1 * f8hi(u1.w);
    }

    // overflow edges (rare): slot-0 lanes only, so reduction counts them once
    int no = *ovCnt;
    for (int k = 0; k < no; ++k) {
        uint2 o = ov[k];
        if ((int)o.x == node && slot == 0) {
            uint4 u = ts16[((int)(o.y >> 15) << 3) + f];
            float w = (float)(o.y & 32767u) * WINV;
            f32x2 W = (f32x2){w, w};
            acc[0] += W * f8lo(u.x); acc[1] += W * f8hi(u.x);
            acc[2] += W * f8lo(u.y); acc[3] += W * f8hi(u.y);
            acc[4] += W * f8lo(u.z); acc[5] += W * f8hi(u.z);
            acc[6] += W * f8lo(u.w); acc[7] += W * f8hi(u.w);
        }
    }

    // reduce across the 4 edge slots (lanes hl^8, hl^16)
#pragma unroll
    for (int k = 0; k < 8; ++k) {
        f32x2 t;
        t.x = __shfl_xor(acc[k].x, 8);  t.y = __shfl_xor(acc[k].y, 8);
        acc[k] += t;
        t.x = __shfl_xor(acc[k].x, 16); t.y = __shfl_xor(acc[k].y, 16);
        acc[k] += t;
    }

    if (slot == 0) {   // lanes hl<8 hold chunk f; epilogue + write
        float di = dinv[node];
        float r[16];
#pragma unroll
        for (int k = 0; k < 8; ++k) {
            float4 bb = bias[f * 4 + (k >> 1)];
            float b0 = (k & 1) ? bb.z : bb.x;
            float b1 = (k & 1) ? bb.w : bb.y;
            r[2 * k]     = acc[k].x * di + b0;
            r[2 * k + 1] = acc[k].y * di + b1;
        }
        if (RES) {
            uint4 q0 = residual[(node << 4) + f * 2];
            uint4 q1 = residual[(node << 4) + f * 2 + 1];
            r[0] += blo(q0.x);  r[1] += bhi(q0.x);
            r[2] += blo(q0.y);  r[3] += bhi(q0.y);
            r[4] += blo(q0.z);  r[5] += bhi(q0.z);
            r[6] += blo(q0.w);  r[7] += bhi(q0.w);
            r[8] += blo(q1.x);  r[9] += bhi(q1.x);
            r[10] += blo(q1.y); r[11] += bhi(q1.y);
            r[12] += blo(q1.z); r[13] += bhi(q1.z);
            r[14] += blo(q1.w); r[15] += bhi(q1.w);
        }
        if (RELU) {
#pragma unroll
            for (int k = 0; k < 16; ++k) r[k] = fmaxf(r[k], 0.f);
        }
        bf16x8 o0, o1;
#pragma unroll
        for (int k = 0; k < 8; ++k) { o0[k] = (bf16_t)r[k]; o1[k] = (bf16_t)r[8 + k]; }
        out[(node << 4) + f * 2]     = *(uint4*)&o0;
        out[(node << 4) + f * 2 + 1] = *(uint4*)&o1;
    }
}

// ---------------- classifier: z = h@Wc1 + bc1; LN; ReLU; out = z@Wc2 + bc2 ----------------

__global__ __launch_bounds__(256) void classifierK(
    const bf16_t* __restrict__ A, const bf16_t* __restrict__ WT,
    const float* __restrict__ bc1, const float* __restrict__ g,
    const float* __restrict__ b, const float* __restrict__ Wc2,
    const float* __restrict__ bc2, float* __restrict__ out, int nrows)
{
    __shared__ __align__(16) bf16_t Bs[128 * 136];
    __shared__ float sB[128], sG[128], sLb[128], sW2[384];
    int tid = threadIdx.x;
    int rb = blockIdx.x * 64;

    {
        const uint4* src = (const uint4*)WT;
        uint4* dst = (uint4*)Bs;
        for (int i = tid; i < 128 * 17; i += 256) dst[i] = src[i];
    }
    if (tid < 128) { sB[tid] = bc1[tid]; sG[tid] = g[tid]; sLb[tid] = b[tid]; }
    for (int i = tid; i < 384; i += 256) sW2[i] = Wc2[i];

    int lane = tid & 63;
    int wid = tid >> 6;
    int m = lane & 15, q = lane >> 4;
    int rowL = min(rb + wid * 16 + m, nrows - 1);

    bf16x8 af[4];
#pragma unroll
    for (int kk = 0; kk < 4; ++kk)
        af[kk] = ((const bf16x8*)A)[rowL * 16 + q + kk * 4];

    __syncthreads();

    f32x4 acc[8];
#pragma unroll
    for (int c = 0; c < 8; ++c) acc[c] = (f32x4){0.f, 0.f, 0.f, 0.f};
#pragma unroll
    for (int kk = 0; kk < 4; ++kk) {
#pragma unroll
        for (int c = 0; c < 8; ++c) {
            bf16x8 bfr = *(const bf16x8*)&Bs[(c * 16 + m) * 136 + q * 8 + kk * 32];
            acc[c] = __builtin_amdgcn_mfma_f32_16x16x32_bf16(af[kk], bfr, acc[c], 0, 0, 0);
        }
    }

    int r0 = rb + wid * 16 + q * 4;
#pragma unroll
    for (int i = 0; i < 4; ++i) {
        float s1 = 0.f, s2 = 0.f;
#pragma unroll
        for (int c = 0; c < 8; ++c) {
            float z = acc[c][i] + sB[c * 16 + m];
            acc[c][i] = z;
            s1 += z; s2 += z * z;
        }
#pragma unroll
        for (int off = 1; off < 16; off <<= 1) {
            s1 += __shfl_xor(s1, off);
            s2 += __shfl_xor(s2, off);
        }
        float mu = s1 * (1.f / 128.f);
        float var = s2 * (1.f / 128.f) - mu * mu;
        float rstd = rsqrtf(var + EPS_LN);
        float p0 = 0.f, p1 = 0.f, p2 = 0.f;
#pragma unroll
        for (int c = 0; c < 8; ++c) {
            int j = c * 16 + m;
            float zn = (acc[c][i] - mu) * rstd * sG[j] + sLb[j];
            zn = fmaxf(zn, 0.f);
            p0 += zn * sW2[j * 3 + 0];
            p1 += zn * sW2[j * 3 + 1];
            p2 += zn * sW2[j * 3 + 2];
        }
#pragma unroll
        for (int off = 1; off < 16; off <<= 1) {
            p0 += __shfl_xor(p0, off);
            p1 += __shfl_xor(p1, off);
            p2 += __shfl_xor(p2, off);
        }
        int r = r0 + i;
        if (m == 0 && r < nrows) {
            out[r * 3 + 0] = p0 + bc2[0];
            out[r * 3 + 1] = p1 + bc2[1];
            out[r * 3 + 2] = p2 + bc2[2];
        }
    }
}

// ---------------- launch ----------------

extern "C" void kernel_launch(void* const* d_in, const int* in_sizes, int n_in,
                              void* d_out, int out_size, void* d_ws, size_t ws_size,
                              hipStream_t stream) {
    const float* x      = (const float*)d_in[0];
    const int*   ei     = (const int*)d_in[1];
    const float* ea     = (const float*)d_in[2];
    const float* W_pre  = (const float*)d_in[3];
    const float* b_pre  = (const float*)d_in[4];
    const float* bn_g   = (const float*)d_in[5];
    const float* bn_b   = (const float*)d_in[6];
    const float* bn_m   = (const float*)d_in[7];
    const float* bn_v   = (const float*)d_in[8];
    const float* W1     = (const float*)d_in[9];
    const float* b1     = (const float*)d_in[10];
    const float* W2     = (const float*)d_in[11];
    const float* b2     = (const float*)d_in[12];
    const float* Wc1    = (const float*)d_in[13];
    const float* bc1    = (const float*)d_in[14];
    const float* ln_g   = (const float*)d_in[15];
    const float* ln_b   = (const float*)d_in[16];
    const float* Wc2    = (const float*)d_in[17];
    const float* bc2    = (const float*)d_in[18];
    float* outp = (float*)d_out;

    const int N = in_sizes[0] / 128;
    const int E = in_sizes[2];

    char* p = (char*)d_ws;
    auto alloc = [&](size_t bytes) -> void* {
        void* r = (void*)p;
        p += (bytes + 255) & ~(size_t)255;
        return r;
    };
    bf16_t*   h0    = (bf16_t*)alloc((size_t)N * 128 * 2);
    bf16_t*   bufB  = (bf16_t*)alloc((size_t)N * 128 * 2);
    unsigned* ts8   = (unsigned*)alloc((size_t)N * 128);
    float*    dinv  = (float*)alloc((size_t)N * 4);
    int*      cnt   = (int*)alloc((size_t)N * 4);
    int*      ovCnt = (int*)alloc(256);
    uint2*    ov    = (uint2*)alloc((size_t)4096 * 8);
    unsigned* slots = (unsigned*)alloc((size_t)N * SLOTS * 4);
    bf16_t*   WT    = (bf16_t*)alloc((size_t)4 * 128 * 136 * 2);

    bf16_t* WT_pre = WT + 0 * 128 * 136;
    bf16_t* WT_1   = WT + 1 * 128 * 136;
    bf16_t* WT_2   = WT + 2 * 128 * 136;
    bf16_t* WT_c1  = WT + 3 * 128 * 136;

    int gE = (E + 255) / 256;
    int gG = (N + 63) / 64;
    int gH = (N + 7) / 8;
    int gP = (max(N, 65536) + 255) / 256;
    int range = (N + NPASS - 1) / NPASS;

    prepK<<<gP, 256, 0, stream>>>(W_pre, W1, W2, Wc1, WT, cnt, ovCnt, N);
    fillAllK<<<NPASS * gE, 256, 0, stream>>>(ei, ea, cnt, slots, ov, ovCnt, E, gE, range);
    degDinvK<<<gH, 256, 0, stream>>>(slots, cnt, ov, ovCnt, dinv, N);

    // h0 = relu(bn(x@W_pre + b_pre))
    gemm128K<0, float><<<gG, 256, 0, stream>>>(x, WT_pre, h0, nullptr, b_pre, bn_m, bn_v, bn_g, bn_b, nullptr, N);
    // conv1: ts8 = fp8(dinv * (h0@W1))
    gemm128K<1, bf16_t><<<gG, 256, 0, stream>>>(h0, WT_1, nullptr, ts8, nullptr, nullptr, nullptr, nullptr, nullptr, dinv, N);
    aggK<1, 0><<<gH, 256, 0, stream>>>((const uint4*)ts8, slots, cnt, dinv, (const float4*)b1,
                                       nullptr, (uint4*)bufB, ov, ovCnt, N);
    // conv2 (+residual h0)
    gemm128K<1, bf16_t><<<gG, 256, 0, stream>>>(bufB, WT_2, nullptr, ts8, nullptr, nullptr, nullptr, nullptr, nullptr, dinv, N);
    aggK<0, 1><<<gH, 256, 0, stream>>>((const uint4*)ts8, slots, cnt, dinv, (const float4*)b2,
                                       (const uint4*)h0, (uint4*)bufB, ov, ovCnt, N);
    // classifier: out = relu(LN(h@Wc1 + bc1)) @ Wc2 + bc2
    classifierK<<<gG, 256, 0, stream>>>(bufB, WT_c1, bc1, ln_g, ln_b, Wc2, bc2, outp, N);
}

// Round 10
// 381.328 us; speedup vs baseline: 1.4279x; 1.0362x over previous
//
#include <hip/hip_runtime.h>
#include <hip/hip_bf16.h>

typedef __bf16 bf16_t;
typedef bf16_t bf16x8 __attribute__((ext_vector_type(8)));
typedef bf16_t bf16x4 __attribute__((ext_vector_type(4)));
typedef float f32x4 __attribute__((ext_vector_type(4)));
typedef float f32x2 __attribute__((ext_vector_type(2)));

#define EPS_BN 1e-5f
#define EPS_LN 1e-5f
#define SLOTS 32
#define WSCALE 32767.f
#define WINV (1.f / 32767.f)

__device__ __forceinline__ float blo(unsigned u) { return __uint_as_float(u << 16); }
__device__ __forceinline__ float bhi(unsigned u) { return __uint_as_float(u & 0xFFFF0000u); }
__device__ __forceinline__ f32x2 f8lo(unsigned u) { return __builtin_amdgcn_cvt_pk_f32_fp8((int)u, false); }
__device__ __forceinline__ f32x2 f8hi(unsigned u) { return __builtin_amdgcn_cvt_pk_f32_fp8((int)u, true); }

// ---------------- prep: zero cnt/ovCnt + convert 4x W[i][o] fp32 -> WT[o*136+i] bf16 ----------------

__global__ void prepK(const float* __restrict__ W0, const float* __restrict__ W1,
                      const float* __restrict__ W2, const float* __restrict__ W3,
                      bf16_t* __restrict__ WT, int* __restrict__ cnt,
                      int* __restrict__ ovCnt, int n) {
    int flat = blockIdx.x * 256 + threadIdx.x;
    if (flat < n) cnt[flat] = 0;
    if (flat == 0) *ovCnt = 0;
    if (flat < 65536) {
        int which = flat >> 14, r = flat & 16383;
        const float* W = (which == 0) ? W0 : (which == 1) ? W1 : (which == 2) ? W2 : W3;
        int i = r >> 7, o = r & 127;
        WT[which * 128 * 136 + o * 136 + i] = (bf16_t)W[r];
    }
}

// ---------------- adjacency fill: XCD-affine dst-range partitioning ----------------
// pass = blockIdx & 7 maps ~to XCD (round-robin dispatch heuristic). Each dst range
// is then written/atomically-updated by ONE XCD only -> single dirty L2 copy, local
// atomics. slot entry: (src<<15) | round(w*32767).

__global__ __launch_bounds__(256) void fillXcdK(
    const int* __restrict__ ei, const float* __restrict__ ea,
    int* __restrict__ cnt, unsigned* __restrict__ slots,
    uint2* __restrict__ ov, int* __restrict__ ovCnt, int E, int range)
{
    int pass = blockIdx.x & 7;
    int blk = blockIdx.x >> 3;
    int e = blk * 256 + threadIdx.x;
    if (e >= E) return;
    int d = ei[E + e];          // edge_index[1][e]
    int lo = pass * range;
    if (d - lo < 0 || d - lo >= range) return;
    int s = ei[e];              // edge_index[0][e]
    unsigned wq = __float2uint_rn(ea[e] * WSCALE);
    unsigned pk = ((unsigned)s << 15) | wq;
    int pos = atomicAdd(&cnt[d], 1);
    if (pos < SLOTS) {
        slots[(d << 5) + pos] = pk;
    } else {
        int o = atomicAdd(ovCnt, 1);
        ov[o] = make_uint2((unsigned)d, pk);
    }
}

// dinv = rsqrt(1 + sum w); pads slot rows to multiple of 8 with (self, w=0)
__global__ __launch_bounds__(256) void degDinvK(
    unsigned* __restrict__ slots, const int* __restrict__ cnt,
    const uint2* __restrict__ ov, const int* __restrict__ ovCnt,
    float* __restrict__ dinv, int n)
{
    int tid = threadIdx.x;
    int node = blockIdx.x * 8 + (tid >> 5);
    int hl = tid & 31;
    if (node >= n) return;
    int c = min(cnt[node], SLOTS);
    int c8 = (c + 7) & ~7;
    float w = 0.f;
    if (hl < c) w = (float)(slots[(node << 5) + hl] & 32767u) * WINV;
    if (hl >= c && hl < c8) slots[(node << 5) + hl] = (unsigned)node << 15;  // pad: self, w=0
    for (int off = 1; off < 32; off <<= 1) w += __shfl_xor(w, off);
    int no = *ovCnt;
    for (int k = 0; k < no; ++k) {
        uint2 o = ov[k];
        if ((int)o.x == node) w += (float)(o.y & 32767u) * WINV;
    }
    if (hl == 0) dinv[node] = rsqrtf(fmaxf(1.f + w, 1e-12f));
}

// ---------------- GEMM: out[r][j] = epilogue( sum_k A[r][k]*W[k][j] ) ----------------
// A fragments loaded directly global->registers; LDS holds only B.
// MODE 0: BN(acc + colBias) then ReLU -> bf16   (input preprocess, A fp32)
// MODE 1: acc * dinv[row] -> fp8 e4m3           (conv message; B cols permuted for packed stores)

template <int MODE, typename AT>
__global__ __launch_bounds__(256) void gemm128K(
    const AT* __restrict__ A, const bf16_t* __restrict__ WT,
    bf16_t* __restrict__ outb, unsigned* __restrict__ out8,
    const float* __restrict__ colBias,
    const float* __restrict__ bnMean, const float* __restrict__ bnVar,
    const float* __restrict__ bnG, const float* __restrict__ bnB,
    const float* __restrict__ dinv, int nrows)
{
    __shared__ __align__(16) bf16_t Bs[128 * 136];   // 34816 B
    int tid = threadIdx.x;
    int rb = blockIdx.x * 64;

    {
        const uint4* src = (const uint4*)WT;
        uint4* dst = (uint4*)Bs;
        if (MODE == 1) {
            for (int i = tid; i < 128 * 17; i += 256) {
                int row = i / 17, k = i - row * 17;
                int so = ((row & 15) << 3) | (row >> 4);
                dst[row * 17 + k] = src[so * 17 + k];
            }
        } else {
            for (int i = tid; i < 128 * 17; i += 256) dst[i] = src[i];
        }
    }

    int lane = tid & 63;
    int wid = tid >> 6;
    int m = lane & 15, q = lane >> 4;
    int myRow = rb + wid * 16 + m;
    int rowL = min(myRow, nrows - 1);

    bf16x8 af[4];
    if constexpr (sizeof(AT) == 4) {
#pragma unroll
        for (int kk = 0; kk < 4; ++kk) {
            float4 v0 = ((const float4*)A)[rowL * 32 + q * 2 + kk * 8];
            float4 v1 = ((const float4*)A)[rowL * 32 + q * 2 + kk * 8 + 1];
            bf16x8 w8;
            w8[0] = (bf16_t)v0.x; w8[1] = (bf16_t)v0.y; w8[2] = (bf16_t)v0.z; w8[3] = (bf16_t)v0.w;
            w8[4] = (bf16_t)v1.x; w8[5] = (bf16_t)v1.y; w8[6] = (bf16_t)v1.z; w8[7] = (bf16_t)v1.w;
            af[kk] = w8;
        }
    } else {
#pragma unroll
        for (int kk = 0; kk < 4; ++kk)
            af[kk] = ((const bf16x8*)A)[rowL * 16 + q + kk * 4];
    }

    __syncthreads();

    f32x4 acc[8];
#pragma unroll
    for (int c = 0; c < 8; ++c) acc[c] = (f32x4){0.f, 0.f, 0.f, 0.f};

#pragma unroll
    for (int kk = 0; kk < 4; ++kk) {
#pragma unroll
        for (int c = 0; c < 8; ++c) {
            bf16x8 bfr = *(const bf16x8*)&Bs[(c * 16 + m) * 136 + q * 8 + kk * 32];
            acc[c] = __builtin_amdgcn_mfma_f32_16x16x32_bf16(af[kk], bfr, acc[c], 0, 0, 0);
        }
    }

    int r0 = rb + wid * 16 + q * 4;
    if (MODE == 1) {
        float dv[4];
#pragma unroll
        for (int i = 0; i < 4; ++i) dv[i] = (r0 + i < nrows) ? dinv[r0 + i] : 0.f;
#pragma unroll
        for (int i = 0; i < 4; ++i) {
            int r = r0 + i;
            if (r < nrows) {
                float v0 = acc[0][i] * dv[i], v1 = acc[1][i] * dv[i];
                float v2 = acc[2][i] * dv[i], v3 = acc[3][i] * dv[i];
                float v4 = acc[4][i] * dv[i], v5 = acc[5][i] * dv[i];
                float v6 = acc[6][i] * dv[i], v7 = acc[7][i] * dv[i];
                int lo = __builtin_amdgcn_cvt_pk_fp8_f32(v0, v1, 0, false);
                lo = __builtin_amdgcn_cvt_pk_fp8_f32(v2, v3, lo, true);
                int hi = __builtin_amdgcn_cvt_pk_fp8_f32(v4, v5, 0, false);
                hi = __builtin_amdgcn_cvt_pk_fp8_f32(v6, v7, hi, true);
                ((uint2*)out8)[(r << 4) | m] = make_uint2((unsigned)lo, (unsigned)hi);
            }
        }
    } else {
#pragma unroll
        for (int c = 0; c < 8; ++c) {
            int j = c * 16 + m;
            float cb = colBias[j];
            float rs = rsqrtf(bnVar[j] + EPS_BN);
            float scale = bnG[j] * rs;
            float shift = bnB[j] - bnMean[j] * scale;
#pragma unroll
            for (int i = 0; i < 4; ++i) {
                int r = r0 + i;
                if (r < nrows) {
                    float v = (acc[c][i] + cb) * scale + shift;
                    outb[r * 128 + j] = (bf16_t)fmaxf(v, 0.f);
                }
            }
        }
    }
}

// ---------------- aggregation (half-wave per node, wide fp8 gather, branchless) ----------------

template <int RELU, int RES>
__global__ __launch_bounds__(256) void aggK(
    const uint4* __restrict__ ts16, const unsigned* __restrict__ slots,
    const int* __restrict__ cnt, const float* __restrict__ dinv,
    const float4* __restrict__ bias, const uint4* __restrict__ residual,
    uint4* __restrict__ out,
    const uint2* __restrict__ ov, const int* __restrict__ ovCnt, int n)
{
    int tid = threadIdx.x;
    int node = blockIdx.x * 8 + (tid >> 5);
    int hl = tid & 31;
    int hb = tid & 32;
    if (node >= n) return;
    int slot = hl >> 3;
    int f = hl & 7;
    int nb = node << 5;

    int c8 = (min(cnt[node], SLOTS) + 7) & ~7;
    unsigned my = slots[nb | hl];
    float myw = (float)(my & 32767u) * WINV;
    int myoff = (int)(my >> 15) << 3;     // uint4 units: src*8

    f32x2 acc[8];
#pragma unroll
    for (int k = 0; k < 8; ++k) acc[k] = (f32x2){0.f, 0.f};

    // self-loop row folded into slot-1 lanes (weight 1), overlaps the gather loop
    if (slot == 1) {
        uint4 su = ts16[(node << 3) + f];
        acc[0] += f8lo(su.x); acc[1] += f8hi(su.x);
        acc[2] += f8lo(su.y); acc[3] += f8hi(su.y);
        acc[4] += f8lo(su.z); acc[5] += f8hi(su.z);
        acc[6] += f8lo(su.w); acc[7] += f8hi(su.w);
    }

    for (int j = 0; j < c8; j += 8) {
        int s0 = hb + j + slot;
        int s1 = s0 + 4;
        int o0 = __shfl(myoff, s0);
        int o1 = __shfl(myoff, s1);
        float w0 = __shfl(myw, s0);
        float w1 = __shfl(myw, s1);
        uint4 u0 = ts16[o0 + f];
        uint4 u1 = ts16[o1 + f];
        f32x2 W0 = (f32x2){w0, w0}, W1 = (f32x2){w1, w1};
        acc[0] += W0 * f8lo(u0.x) + W1 * f8lo(u1.x);
        acc[1] += W0 * f8hi(u0.x) + W1 * f8hi(u1.x);
        acc[2] += W0 * f8lo(u0.y) + W1 * f8lo(u1.y);
        acc[3] += W0 * f8hi(u0.y) + W1 * f8hi(u1.y);
        acc[4] += W0 * f8lo(u0.z) + W1 * f8lo(u1.z);
        acc[5] += W0 * f8hi(u0.z) + W1 * f8hi(u1.z);
        acc[6] += W0 * f8lo(u0.w) + W1 * f8lo(u1.w);
        acc[7] += W0 * f8hi(u0.w) + W1 * f8hi(u1.w);
    }

    // overflow edges (rare): slot-0 lanes only, so reduction counts them once
    int no = *ovCnt;
    for (int k = 0; k < no; ++k) {
        uint2 o = ov[k];
        if ((int)o.x == node && slot == 0) {
            uint4 u = ts16[((int)(o.y >> 15) << 3) + f];
            float w = (float)(o.y & 32767u) * WINV;
            f32x2 W = (f32x2){w, w};
            acc[0] += W * f8lo(u.x); acc[1] += W * f8hi(u.x);
            acc[2] += W * f8lo(u.y); acc[3] += W * f8hi(u.y);
            acc[4] += W * f8lo(u.z); acc[5] += W * f8hi(u.z);
            acc[6] += W * f8lo(u.w); acc[7] += W * f8hi(u.w);
        }
    }

    // reduce across the 4 edge slots (lanes hl^8, hl^16)
#pragma unroll
    for (int k = 0; k < 8; ++k) {
        f32x2 t;
        t.x = __shfl_xor(acc[k].x, 8);  t.y = __shfl_xor(acc[k].y, 8);
        acc[k] += t;
        t.x = __shfl_xor(acc[k].x, 16); t.y = __shfl_xor(acc[k].y, 16);
        acc[k] += t;
    }

    if (slot == 0) {   // lanes hl<8 hold chunk f; epilogue + write
        float di = dinv[node];
        float r[16];
#pragma unroll
        for (int k = 0; k < 8; ++k) {
            float4 bb = bias[f * 4 + (k >> 1)];
            float b0 = (k & 1) ? bb.z : bb.x;
            float b1 = (k & 1) ? bb.w : bb.y;
            r[2 * k]     = acc[k].x * di + b0;
            r[2 * k + 1] = acc[k].y * di + b1;
        }
        if (RES) {
            uint4 q0 = residual[(node << 4) + f * 2];
            uint4 q1 = residual[(node << 4) + f * 2 + 1];
            r[0] += blo(q0.x);  r[1] += bhi(q0.x);
            r[2] += blo(q0.y);  r[3] += bhi(q0.y);
            r[4] += blo(q0.z);  r[5] += bhi(q0.z);
            r[6] += blo(q0.w);  r[7] += bhi(q0.w);
            r[8] += blo(q1.x);  r[9] += bhi(q1.x);
            r[10] += blo(q1.y); r[11] += bhi(q1.y);
            r[12] += blo(q1.z); r[13] += bhi(q1.z);
            r[14] += blo(q1.w); r[15] += bhi(q1.w);
        }
        if (RELU) {
#pragma unroll
            for (int k = 0; k < 16; ++k) r[k] = fmaxf(r[k], 0.f);
        }
        bf16x8 o0, o1;
#pragma unroll
        for (int k = 0; k < 8; ++k) { o0[k] = (bf16_t)r[k]; o1[k] = (bf16_t)r[8 + k]; }
        out[(node << 4) + f * 2]     = *(uint4*)&o0;
        out[(node << 4) + f * 2 + 1] = *(uint4*)&o1;
    }
}

// ---------------- classifier: z = h@Wc1 + bc1; LN; ReLU; out = z@Wc2 + bc2 ----------------

__global__ __launch_bounds__(256) void classifierK(
    const bf16_t* __restrict__ A, const bf16_t* __restrict__ WT,
    const float* __restrict__ bc1, const float* __restrict__ g,
    const float* __restrict__ b, const float* __restrict__ Wc2,
    const float* __restrict__ bc2, float* __restrict__ out, int nrows)
{
    __shared__ __align__(16) bf16_t Bs[128 * 136];
    __shared__ float sB[128], sG[128], sLb[128], sW2[384];
    int tid = threadIdx.x;
    int rb = blockIdx.x * 64;

    {
        const uint4* src = (const uint4*)WT;
        uint4* dst = (uint4*)Bs;
        for (int i = tid; i < 128 * 17; i += 256) dst[i] = src[i];
    }
    if (tid < 128) { sB[tid] = bc1[tid]; sG[tid] = g[tid]; sLb[tid] = b[tid]; }
    for (int i = tid; i < 384; i += 256) sW2[i] = Wc2[i];

    int lane = tid & 63;
    int wid = tid >> 6;
    int m = lane & 15, q = lane >> 4;
    int rowL = min(rb + wid * 16 + m, nrows - 1);

    bf16x8 af[4];
#pragma unroll
    for (int kk = 0; kk < 4; ++kk)
        af[kk] = ((const bf16x8*)A)[rowL * 16 + q + kk * 4];

    __syncthreads();

    f32x4 acc[8];
#pragma unroll
    for (int c = 0; c < 8; ++c) acc[c] = (f32x4){0.f, 0.f, 0.f, 0.f};
#pragma unroll
    for (int kk = 0; kk < 4; ++kk) {
#pragma unroll
        for (int c = 0; c < 8; ++c) {
            bf16x8 bfr = *(const bf16x8*)&Bs[(c * 16 + m) * 136 + q * 8 + kk * 32];
            acc[c] = __builtin_amdgcn_mfma_f32_16x16x32_bf16(af[kk], bfr, acc[c], 0, 0, 0);
        }
    }

    int r0 = rb + wid * 16 + q * 4;
#pragma unroll
    for (int i = 0; i < 4; ++i) {
        float s1 = 0.f, s2 = 0.f;
#pragma unroll
        for (int c = 0; c < 8; ++c) {
            float z = acc[c][i] + sB[c * 16 + m];
            acc[c][i] = z;
            s1 += z; s2 += z * z;
        }
#pragma unroll
        for (int off = 1; off < 16; off <<= 1) {
            s1 += __shfl_xor(s1, off);
            s2 += __shfl_xor(s2, off);
        }
        float mu = s1 * (1.f / 128.f);
        float var = s2 * (1.f / 128.f) - mu * mu;
        float rstd = rsqrtf(var + EPS_LN);
        float p0 = 0.f, p1 = 0.f, p2 = 0.f;
#pragma unroll
        for (int c = 0; c < 8; ++c) {
            int j = c * 16 + m;
            float zn = (acc[c][i] - mu) * rstd * sG[j] + sLb[j];
            zn = fmaxf(zn, 0.f);
            p0 += zn * sW2[j * 3 + 0];
            p1 += zn * sW2[j * 3 + 1];
            p2 += zn * sW2[j * 3 + 2];
        }
#pragma unroll
        for (int off = 1; off < 16; off <<= 1) {
            p0 += __shfl_xor(p0, off);
            p1 += __shfl_xor(p1, off);
            p2 += __shfl_xor(p2, off);
        }
        int r = r0 + i;
        if (m == 0 && r < nrows) {
            out[r * 3 + 0] = p0 + bc2[0];
            out[r * 3 + 1] = p1 + bc2[1];
            out[r * 3 + 2] = p2 + bc2[2];
        }
    }
}

// ---------------- launch ----------------

extern "C" void kernel_launch(void* const* d_in, const int* in_sizes, int n_in,
                              void* d_out, int out_size, void* d_ws, size_t ws_size,
                              hipStream_t stream) {
    const float* x      = (const float*)d_in[0];
    const int*   ei     = (const int*)d_in[1];
    const float* ea     = (const float*)d_in[2];
    const float* W_pre  = (const float*)d_in[3];
    const float* b_pre  = (const float*)d_in[4];
    const float* bn_g   = (const float*)d_in[5];
    const float* bn_b   = (const float*)d_in[6];
    const float* bn_m   = (const float*)d_in[7];
    const float* bn_v   = (const float*)d_in[8];
    const float* W1     = (const float*)d_in[9];
    const float* b1     = (const float*)d_in[10];
    const float* W2     = (const float*)d_in[11];
    const float* b2     = (const float*)d_in[12];
    const float* Wc1    = (const float*)d_in[13];
    const float* bc1    = (const float*)d_in[14];
    const float* ln_g   = (const float*)d_in[15];
    const float* ln_b   = (const float*)d_in[16];
    const float* Wc2    = (const float*)d_in[17];
    const float* bc2    = (const float*)d_in[18];
    float* outp = (float*)d_out;

    const int N = in_sizes[0] / 128;
    const int E = in_sizes[2];

    char* p = (char*)d_ws;
    auto alloc = [&](size_t bytes) -> void* {
        void* r = (void*)p;
        p += (bytes + 255) & ~(size_t)255;
        return r;
    };
    bf16_t*   h0    = (bf16_t*)alloc((size_t)N * 128 * 2);
    bf16_t*   bufB  = (bf16_t*)alloc((size_t)N * 128 * 2);
    unsigned* ts8   = (unsigned*)alloc((size_t)N * 128);
    float*    dinv  = (float*)alloc((size_t)N * 4);
    int*      cnt   = (int*)alloc((size_t)N * 4);
    int*      ovCnt = (int*)alloc(256);
    uint2*    ov    = (uint2*)alloc((size_t)4096 * 8);
    unsigned* slots = (unsigned*)alloc((size_t)N * SLOTS * 4);
    bf16_t*   WT    = (bf16_t*)alloc((size_t)4 * 128 * 136 * 2);

    bf16_t* WT_pre = WT + 0 * 128 * 136;
    bf16_t* WT_1   = WT + 1 * 128 * 136;
    bf16_t* WT_2   = WT + 2 * 128 * 136;
    bf16_t* WT_c1  = WT + 3 * 128 * 136;

    int gE = (E + 255) / 256;
    int gG = (N + 63) / 64;
    int gH = (N + 7) / 8;
    int gP = (max(N, 65536) + 255) / 256;
    int range = (N + 7) / 8;

    prepK<<<gP, 256, 0, stream>>>(W_pre, W1, W2, Wc1, WT, cnt, ovCnt, N);
    fillXcdK<<<8 * gE, 256, 0, stream>>>(ei, ea, cnt, slots, ov, ovCnt, E, range);
    degDinvK<<<gH, 256, 0, stream>>>(slots, cnt, ov, ovCnt, dinv, N);

    // h0 = relu(bn(x@W_pre + b_pre))
    gemm128K<0, float><<<gG, 256, 0, stream>>>(x, WT_pre, h0, nullptr, b_pre, bn_m, bn_v, bn_g, bn_b, nullptr, N);
    // conv1: ts8 = fp8(dinv * (h0@W1))
    gemm128K<1, bf16_t><<<gG, 256, 0, stream>>>(h0, WT_1, nullptr, ts8, nullptr, nullptr, nullptr, nullptr, nullptr, dinv, N);
    aggK<1, 0><<<gH, 256, 0, stream>>>((const uint4*)ts8, slots, cnt, dinv, (const float4*)b1,
                                       nullptr, (uint4*)bufB, ov, ovCnt, N);
    // conv2 (+residual h0)
    gemm128K<1, bf16_t><<<gG, 256, 0, stream>>>(bufB, WT_2, nullptr, ts8, nullptr, nullptr, nullptr, nullptr, nullptr, dinv, N);
    aggK<0, 1><<<gH, 256, 0, stream>>>((const uint4*)ts8, slots, cnt, dinv, (const float4*)b2,
                                       (const uint4*)h0, (uint4*)bufB, ov, ovCnt, N);
    // classifier: out = relu(LN(h@Wc1 + bc1)) @ Wc2 + bc2
    classifierK<<<gG, 256, 0, stream>>>(bufB, WT_c1, bc1, ln_g, ln_b, Wc2, bc2, outp, N);
}